// Round 8
// baseline (217.631 us; speedup 1.0000x reference)
//
#include <hip/hip_runtime.h>

#define HID 512
#define HEADS 8
#define HD 64
#define BATCH 2
#define SEQ 384
#define MROWS (BATCH * SEQ)  // 768
#define KT_N 48              // k'-tiles: 1536 / 32
#define APACK_S8 (48 * KT_N * 64)   // 147456 s8-chunks per packed A (768x1536 bf16)
#define BPACK_S8 (32 * KT_N * 64)   // 98304 s8-chunks per packed B (512x1536 bf16)

// 2*log2(e): Eq = exp2(C1 * qW) == exp(2*qW)
#define C1 2.8853900817779268f
// log2(e)/8: softmax exponent scale (energy = raw/8)
#define SSCL 0.18033688011112043f

typedef __attribute__((ext_vector_type(8))) short s8v;   // 8 bf16 (4 VGPR)
typedef __attribute__((ext_vector_type(4))) float f4v;   // MFMA acc

__device__ __forceinline__ unsigned short bf16_rne(float x) {
    union { float f; unsigned u; } v; v.f = x;
    unsigned r = v.u + 0x7FFFu + ((v.u >> 16) & 1u);
    return (unsigned short)(r >> 16);
}
__device__ __forceinline__ float bf16_val(unsigned short h) {
    union { float f; unsigned u; } v; v.u = ((unsigned)h) << 16; return v.f;
}

// ---------------------------------------------------------------------------
// Pack A [768x512 f32] -> A' [768 x 1536 bf16] = [Ah | Ah | Al] in MFMA swizzle
// ---------------------------------------------------------------------------
__device__ __forceinline__ void pack_a_one(const float* __restrict__ src,
                                           s8v* __restrict__ dst, int rem)
{
    int g = rem & 63, m = rem >> 6;           // c = 8g .. 8g+7
    const float4* sp = (const float4*)(src + (size_t)m * HID + g * 8);
    float4 v0 = sp[0], v1 = sp[1];
    float vals[8] = {v0.x, v0.y, v0.z, v0.w, v1.x, v1.y, v1.z, v1.w};
    s8v hi, lo;
    #pragma unroll
    for (int j = 0; j < 8; ++j) {
        unsigned short h = bf16_rne(vals[j]);
        hi[j] = (short)h;
        lo[j] = (short)bf16_rne(vals[j] - bf16_val(h));
    }
    int mt = m >> 4, kt = g >> 2;
    int lanei = (m & 15) | ((g & 3) << 4);
    size_t base = ((size_t)mt * KT_N) * 64 + lanei;
    dst[base + (size_t)kt * 64]        = hi;  // sec1: Ah (x Bh)
    dst[base + (size_t)(16 + kt) * 64] = hi;  // sec2: Ah (x Bl)
    dst[base + (size_t)(32 + kt) * 64] = lo;  // sec3: Al (x Bh)
}

// ---------------------------------------------------------------------------
// Pack W [512x512 f32, (k,n)] -> B' [Bh | Bl | Bh] in MFMA swizzle
// ---------------------------------------------------------------------------
__device__ __forceinline__ void pack_w_store(s8v* __restrict__ dst,
                                             const float vals[8], int kg, int n)
{
    s8v hi, lo;
    #pragma unroll
    for (int j = 0; j < 8; ++j) {
        unsigned short h = bf16_rne(vals[j]);
        hi[j] = (short)h;
        lo[j] = (short)bf16_rne(vals[j] - bf16_val(h));
    }
    int nt = n >> 4, kt = kg >> 2;
    int lanei = (n & 15) | ((kg & 3) << 4);
    size_t base = ((size_t)nt * KT_N) * 64 + lanei;
    dst[base + (size_t)kt * 64]        = hi;  // sec1: Bh
    dst[base + (size_t)(16 + kt) * 64] = lo;  // sec2: Bl
    dst[base + (size_t)(32 + kt) * 64] = hi;  // sec3: Bh
}

__device__ __forceinline__ void pack_w_one(const float* __restrict__ W,
                                           s8v* __restrict__ dst, int rem)
{
    int kg = rem >> 9, n = rem & 511;         // k = 8kg .. 8kg+7
    float vals[8];
    #pragma unroll
    for (int j = 0; j < 8; ++j)
        vals[j] = W[(size_t)(kg * 8 + j) * HID + n];   // coalesced across n
    pack_w_store(dst, vals, kg, n);
}

// fold Wbig(512x512) @ blockdiag(Wsmall 64x64) on the fly, then pack
__device__ __forceinline__ void fold_pack_w_one(const float* __restrict__ Wbig,
                                                const float* __restrict__ Wsmall,
                                                s8v* __restrict__ dst, int rem)
{
    int kg = __builtin_amdgcn_readfirstlane(rem >> 9);
    int n  = rem & 511;
    int h  = __builtin_amdgcn_readfirstlane(n >> 6);
    int d  = n & 63;
    const float* wr = Wbig + (size_t)(kg * 8) * HID + h * HD;
    float acc[8] = {0.f, 0.f, 0.f, 0.f, 0.f, 0.f, 0.f, 0.f};
    #pragma unroll 8
    for (int t = 0; t < 64; ++t) {
        float wv = Wsmall[t * 64 + d];      // coalesced across lanes
        #pragma unroll
        for (int j = 0; j < 8; ++j)
            acc[j] = fmaf(wr[(size_t)j * HID + t], wv, acc[j]);  // uniform
    }
    pack_w_store(dst, acc, kg, n);
}

// ---------------------------------------------------------------------------
// ONE launch for all prep+pack work (no internal dependencies):
// [0,576): A packs q,k,v | [576,704): Wv | [704,832): Wo
// [832,960): fold(Wq,Ww) | [960,1088): fold(Wk,Wu) | [1088]: biases + vv2
// ---------------------------------------------------------------------------
__global__ __launch_bounds__(256) void pack_all_kernel(
    const float* __restrict__ q, const float* __restrict__ k, const float* __restrict__ v,
    const float* __restrict__ Wq, const float* __restrict__ bq,
    const float* __restrict__ Wk, const float* __restrict__ bk,
    const float* __restrict__ Wv, const float* __restrict__ Wo,
    const float* __restrict__ Ww, const float* __restrict__ bw,
    const float* __restrict__ Wu, const float* __restrict__ bu,
    const float* __restrict__ vv,
    s8v* __restrict__ Aq, s8v* __restrict__ Ak, s8v* __restrict__ Av,
    s8v* __restrict__ Bq, s8v* __restrict__ Bk, s8v* __restrict__ Bv, s8v* __restrict__ Bo,
    float* __restrict__ bqe, float* __restrict__ bke, float* __restrict__ vv2)
{
    int bx = blockIdx.x, tid = threadIdx.x;
    if (bx < 576) {
        int p = bx / 192;
        int rem = (bx % 192) * 256 + tid;
        const float* src = (p == 0) ? q : (p == 1) ? k : v;
        s8v* dst = (p == 0) ? Aq : (p == 1) ? Ak : Av;
        pack_a_one(src, dst, rem);
    } else if (bx < 704) {
        pack_w_one(Wv, Bv, (bx - 576) * 256 + tid);
    } else if (bx < 832) {
        pack_w_one(Wo, Bo, (bx - 704) * 256 + tid);
    } else if (bx < 960) {
        fold_pack_w_one(Wq, Ww, Bq, (bx - 832) * 256 + tid);
    } else if (bx < 1088) {
        fold_pack_w_one(Wk, Wu, Bk, (bx - 960) * 256 + tid);
    } else {
        for (int i = tid; i < 1088; i += 256) {
            if (i < 512) {
                int h = i >> 6, j = i & 63;
                float s = bw[j];
                for (int t = 0; t < 64; ++t) s = fmaf(bq[h * 64 + t], Ww[t * 64 + j], s);
                bqe[i] = s;
            } else if (i < 1024) {
                int n = i - 512, h = n >> 6, j = n & 63;
                float s = bu[j];
                for (int t = 0; t < 64; ++t) s = fmaf(bk[h * 64 + t], Wu[t * 64 + j], s);
                bke[n] = s;
            } else {
                vv2[i - 1024] = -2.0f * vv[i - 1024];
            }
        }
    }
}

// ---------------------------------------------------------------------------
// MFMA GEMM: one WAVE per block (64 thr), 32x32 tile (2x2 MFMA 16x16x32).
// No LDS, no barriers; fragments loaded coalesced b128 from swizzled packs.
// MODE 0: plain  MODE 1: exp2(C1*y)  MODE 2: exp2 + transposed-packed Ek4
// ---------------------------------------------------------------------------
template <int MODE>
__device__ __forceinline__ void mfma_gemm_body(
    const s8v* __restrict__ Ap, const s8v* __restrict__ Bp,
    const float* __restrict__ bias, float* __restrict__ out,
    int mt0, int nt0)
{
    int lane = threadIdx.x & 63;

    const s8v* a0p = Ap + (size_t)(mt0 * KT_N) * 64 + lane;
    const s8v* a1p = a0p + (size_t)KT_N * 64;
    const s8v* b0p = Bp + (size_t)(nt0 * KT_N) * 64 + lane;
    const s8v* b1p = b0p + (size_t)KT_N * 64;

    f4v acc00 = {0.f, 0.f, 0.f, 0.f};
    f4v acc01 = {0.f, 0.f, 0.f, 0.f};
    f4v acc10 = {0.f, 0.f, 0.f, 0.f};
    f4v acc11 = {0.f, 0.f, 0.f, 0.f};

    s8v xa0 = a0p[0], xa1 = a1p[0], xb0 = b0p[0], xb1 = b1p[0];
    #pragma unroll 1
    for (int kt = 0; kt < KT_N; kt += 2) {
        int o1 = (kt + 1) * 64;
        s8v ya0 = a0p[o1], ya1 = a1p[o1], yb0 = b0p[o1], yb1 = b1p[o1];
        acc00 = __builtin_amdgcn_mfma_f32_16x16x32_bf16(xa0, xb0, acc00, 0, 0, 0);
        acc01 = __builtin_amdgcn_mfma_f32_16x16x32_bf16(xa0, xb1, acc01, 0, 0, 0);
        acc10 = __builtin_amdgcn_mfma_f32_16x16x32_bf16(xa1, xb0, acc10, 0, 0, 0);
        acc11 = __builtin_amdgcn_mfma_f32_16x16x32_bf16(xa1, xb1, acc11, 0, 0, 0);
        int o2 = (kt + 2 < KT_N) ? (kt + 2) * 64 : 0;   // tail wrap: harmless load
        xa0 = a0p[o2]; xa1 = a1p[o2]; xb0 = b0p[o2]; xb1 = b1p[o2];
        acc00 = __builtin_amdgcn_mfma_f32_16x16x32_bf16(ya0, yb0, acc00, 0, 0, 0);
        acc01 = __builtin_amdgcn_mfma_f32_16x16x32_bf16(ya0, yb1, acc01, 0, 0, 0);
        acc10 = __builtin_amdgcn_mfma_f32_16x16x32_bf16(ya1, yb0, acc10, 0, 0, 0);
        acc11 = __builtin_amdgcn_mfma_f32_16x16x32_bf16(ya1, yb1, acc11, 0, 0, 0);
    }

    // Epilogue. C/D layout: row = quad*4 + reg, col = lane&15.
    int quad = lane >> 4, c16 = lane & 15;
    int col0 = nt0 * 16 + c16, col1 = col0 + 16;
    float bias0 = bias[col0], bias1 = bias[col1];
    int row0 = mt0 * 16 + quad * 4;
    int row1 = row0 + 16;

    #pragma unroll
    for (int r = 0; r < 4; ++r) {
        float y;
        #define WR(ROW, COL, Y)                                                     \
        {                                                                           \
            float yy = (Y);                                                         \
            if (MODE != 0) yy = __builtin_amdgcn_exp2f(C1 * yy);                    \
            if (MODE == 2) {                                                        \
                int b2 = (ROW) / SEQ, kk = (ROW) - b2 * SEQ;                        \
                int hh = (COL) >> 6, dd = (COL) & 63;                               \
                out[(((size_t)((b2 * 8 + hh) * 16 + (dd >> 2)) * SEQ + kk) << 2)    \
                    + (dd & 3)] = yy;                                               \
            } else {                                                                \
                out[(size_t)(ROW) * HID + (COL)] = yy;                              \
            }                                                                       \
        }
        y = acc00[r] + bias0; WR(row0 + r, col0, y);
        y = acc01[r] + bias1; WR(row0 + r, col1, y);
        y = acc10[r] + bias0; WR(row1 + r, col0, y);
        y = acc11[r] + bias1; WR(row1 + r, col1, y);
        #undef WR
    }
}

__global__ __launch_bounds__(64) void proj3_mfma_kernel(
    const s8v* __restrict__ Aq, const s8v* __restrict__ Ak, const s8v* __restrict__ Av,
    const s8v* __restrict__ Bq, const s8v* __restrict__ Bk, const s8v* __restrict__ Bv,
    const float* __restrict__ bqe, const float* __restrict__ bke, const float* __restrict__ bv,
    float* __restrict__ Eq, float* __restrict__ Ek4, float* __restrict__ V)
{
    int p = blockIdx.z;
    int mt0 = blockIdx.x * 2, nt0 = blockIdx.y * 2;
    if (p == 0)      mfma_gemm_body<1>(Aq, Bq, bqe, Eq,  mt0, nt0);
    else if (p == 1) mfma_gemm_body<2>(Ak, Bk, bke, Ek4, mt0, nt0);
    else             mfma_gemm_body<0>(Av, Bv, bv,  V,   mt0, nt0);
}

__global__ __launch_bounds__(64) void out_mfma_kernel(
    const s8v* __restrict__ Ax, const s8v* __restrict__ Bo,
    const float* __restrict__ bo, float* __restrict__ out)
{
    mfma_gemm_body<0>(Ax, Bo, bo, out, blockIdx.x * 2, blockIdx.y * 2);
}

// ---------------------------------------------------------------------------
// attention v5: k-split. Block = 4 waves = 2 q-pairs x 2 k-halves.
// grid (96, 16) = 1536 blocks = 6 blocks/CU (75% occupancy).
// Each wave: 2 q rows, 192 k values. Cross-wave softmax/x-combine via LDS.
// Epilogue packs X directly into Ax (bf16 3-term MFMA swizzle).
// ---------------------------------------------------------------------------
__global__ __launch_bounds__(256, 6) void attn_kernel(
    const float* __restrict__ Eq, const float* __restrict__ Ek4,
    const float* __restrict__ V, const float* __restrict__ vv2,
    float* __restrict__ attnOut, s8v* __restrict__ Ax)
{
    __shared__ float2 aP[2][SEQ];       // [pair][k]
    __shared__ float  red[2][2][2][2];  // [m/s][pair][q01][khalf]
    __shared__ float4 xred[2][2][16];   // [pair][q01][d4] partials from khalf==1

    int bh = blockIdx.y;
    int b = bh >> 3, h = bh & 7;
    int tid = threadIdx.x;
    int wave = __builtin_amdgcn_readfirstlane(tid >> 6);
    int lane = tid & 63;
    int pair = wave >> 1, khalf = wave & 1;
    int q0 = blockIdx.x * 4 + pair * 2, q1 = q0 + 1;

    const float* eq0 = Eq + (size_t)(b * SEQ + q0) * HID + h * HD;  // uniform
    const float* eq1 = eq0 + HID;
    // this wave's k-half: kt_global = khalf*3 + kt, kt in [0,3)
    const float4* ekbase = (const float4*)Ek4 + (size_t)bh * 16 * SEQ
                         + khalf * 3 * 64 + lane;

    float e0[3] = {0.f, 0.f, 0.f}, e1[3] = {0.f, 0.f, 0.f};

    // rotating 1-group-ahead prefetch, primed once, flows across c boundaries
    float4 k0 = ekbase[0], k1 = ekbase[SEQ], k2 = ekbase[2 * SEQ], k3 = ekbase[3 * SEQ];
    #pragma unroll 1
    for (int c = 0; c < 4; ++c) {
        float g0[16], g1[16], w[16];
        #pragma unroll
        for (int j = 0; j < 16; ++j) {
            g0[j] = eq0[c * 16 + j];   // wave-uniform -> s_load
            g1[j] = eq1[c * 16 + j];
            w[j]  = vv2[c * 16 + j];
        }
        #pragma unroll
        for (int kt = 0; kt < 3; ++kt) {
            float4 n0, n1, n2, n3;
            if (!(c == 3 && kt == 2)) {
                const float4* np = (kt < 2) ? (ekbase + c * 4 * SEQ + (kt + 1) * 64)
                                            : (ekbase + (c + 1) * 4 * SEQ);
                n0 = np[0]; n1 = np[SEQ]; n2 = np[2 * SEQ]; n3 = np[3 * SEQ];
            }
            float r0 = e0[kt], r1 = e1[kt];
            #define EN(J, KV)                                                      \
            {                                                                      \
                float t0 = __builtin_amdgcn_rcpf(fmaf(g0[J], (KV), 1.f));          \
                float t1 = __builtin_amdgcn_rcpf(fmaf(g1[J], (KV), 1.f));          \
                r0 = fmaf(w[J], t0, r0);                                           \
                r1 = fmaf(w[J], t1, r1);                                           \
            }
            EN(0,  k0.x) EN(1,  k0.y) EN(2,  k0.z) EN(3,  k0.w)
            EN(4,  k1.x) EN(5,  k1.y) EN(6,  k1.z) EN(7,  k1.w)
            EN(8,  k2.x) EN(9,  k2.y) EN(10, k2.z) EN(11, k2.w)
            EN(12, k3.x) EN(13, k3.y) EN(14, k3.z) EN(15, k3.w)
            #undef EN
            e0[kt] = r0; e1[kt] = r1;
            k0 = n0; k1 = n1; k2 = n2; k3 = n3;
        }
    }

    // local max over this half, then cross-wave combine
    float m0 = fmaxf(fmaxf(e0[0], e0[1]), e0[2]);
    float m1 = fmaxf(fmaxf(e1[0], e1[1]), e1[2]);
    #pragma unroll
    for (int off = 1; off < 64; off <<= 1) {
        m0 = fmaxf(m0, __shfl_xor(m0, off));
        m1 = fmaxf(m1, __shfl_xor(m1, off));
    }
    if (lane == 0) { red[0][pair][0][khalf] = m0; red[0][pair][1][khalf] = m1; }
    __syncthreads();
    m0 = fmaxf(red[0][pair][0][0], red[0][pair][0][1]);
    m1 = fmaxf(red[0][pair][1][0], red[0][pair][1][1]);

    float a0[3], a1[3], s0 = 0.f, s1 = 0.f;
    #pragma unroll
    for (int t = 0; t < 3; ++t) {
        a0[t] = __builtin_amdgcn_exp2f((e0[t] - m0) * SSCL); s0 += a0[t];
        a1[t] = __builtin_amdgcn_exp2f((e1[t] - m1) * SSCL); s1 += a1[t];
    }
    #pragma unroll
    for (int off = 1; off < 64; off <<= 1) {
        s0 += __shfl_xor(s0, off);
        s1 += __shfl_xor(s1, off);
    }
    if (lane == 0) { red[1][pair][0][khalf] = s0; red[1][pair][1][khalf] = s1; }
    __syncthreads();
    s0 = red[1][pair][0][0] + red[1][pair][0][1];
    s1 = red[1][pair][1][0] + red[1][pair][1][1];
    float z0 = __builtin_amdgcn_rcpf(s0), z1 = __builtin_amdgcn_rcpf(s1);

    size_t abase = (size_t)bh * SEQ * SEQ + (size_t)q0 * SEQ + khalf * 192;
    #pragma unroll
    for (int t = 0; t < 3; ++t) {
        float v0 = a0[t] * z0, v1 = a1[t] * z1;
        attnOut[abase + t * 64 + lane] = v0;
        attnOut[abase + SEQ + t * 64 + lane] = v1;
        aP[pair][khalf * 192 + t * 64 + lane] = make_float2(v0, v1);
    }
    // aP[pair][own half] written and read by the same wave -> no barrier yet

    // attn @ V over this wave's k-half: lane = ko*16 + d4p
    int ko = lane >> 4, d4p = lane & 15;
    const float4* vb = (const float4*)&V[(size_t)b * SEQ * HID + h * HD + d4p * 4];
    float4 x0 = make_float4(0.f, 0.f, 0.f, 0.f);
    float4 x1 = make_float4(0.f, 0.f, 0.f, 0.f);
    int kend = khalf * 192 + 192;
    #pragma unroll 8
    for (int k = khalf * 192 + ko; k < kend; k += 4) {
        float4 v = vb[(size_t)k * (HID / 4)];
        float2 a = aP[pair][k];
        x0.x = fmaf(a.x, v.x, x0.x); x0.y = fmaf(a.x, v.y, x0.y);
        x0.z = fmaf(a.x, v.z, x0.z); x0.w = fmaf(a.x, v.w, x0.w);
        x1.x = fmaf(a.y, v.x, x1.x); x1.y = fmaf(a.y, v.y, x1.y);
        x1.z = fmaf(a.y, v.z, x1.z); x1.w = fmaf(a.y, v.w, x1.w);
    }
    #pragma unroll
    for (int off = 16; off < 64; off <<= 1) {
        x0.x += __shfl_xor(x0.x, off); x0.y += __shfl_xor(x0.y, off);
        x0.z += __shfl_xor(x0.z, off); x0.w += __shfl_xor(x0.w, off);
        x1.x += __shfl_xor(x1.x, off); x1.y += __shfl_xor(x1.y, off);
        x1.z += __shfl_xor(x1.z, off); x1.w += __shfl_xor(x1.w, off);
    }
    if (khalf == 1 && ko == 0) {
        xred[pair][0][d4p] = x0;
        xred[pair][1][d4p] = x1;
    }
    __syncthreads();

    // khalf==0 wave combines halves and packs X rows q0/q1 straight into Ax.
    // Lanes 0..15 hold the full row as float4; chunk u (8 floats) = lanes {2u,2u+1}.
    if (khalf == 0 && ko == 0) {
        float4 o0 = xred[pair][0][d4p], o1 = xred[pair][1][d4p];
        x0.x += o0.x; x0.y += o0.y; x0.z += o0.z; x0.w += o0.w;
        x1.x += o1.x; x1.y += o1.y; x1.z += o1.z; x1.w += o1.w;

        float4 p0, p1;
        p0.x = __shfl_xor(x0.x, 1); p0.y = __shfl_xor(x0.y, 1);
        p0.z = __shfl_xor(x0.z, 1); p0.w = __shfl_xor(x0.w, 1);
        p1.x = __shfl_xor(x1.x, 1); p1.y = __shfl_xor(x1.y, 1);
        p1.z = __shfl_xor(x1.z, 1); p1.w = __shfl_xor(x1.w, 1);
        float vals[8];
        int row;
        if ((lane & 1) == 0) {
            vals[0] = x0.x; vals[1] = x0.y; vals[2] = x0.z; vals[3] = x0.w;
            vals[4] = p0.x; vals[5] = p0.y; vals[6] = p0.z; vals[7] = p0.w;
            row = b * SEQ + q0;
        } else {
            vals[0] = p1.x; vals[1] = p1.y; vals[2] = p1.z; vals[3] = p1.w;
            vals[4] = x1.x; vals[5] = x1.y; vals[6] = x1.z; vals[7] = x1.w;
            row = b * SEQ + q1;
        }
        int g = h * 8 + (lane >> 1);   // global 8-col group
        s8v hi, lo;
        #pragma unroll
        for (int j = 0; j < 8; ++j) {
            unsigned short hh = bf16_rne(vals[j]);
            hi[j] = (short)hh;
            lo[j] = (short)bf16_rne(vals[j] - bf16_val(hh));
        }
        int mt = row >> 4, kt2 = g >> 2;
        int lanei = (row & 15) | ((g & 3) << 4);
        size_t base = ((size_t)mt * KT_N) * 64 + lanei;
        Ax[base + (size_t)kt2 * 64]        = hi;
        Ax[base + (size_t)(16 + kt2) * 64] = hi;
        Ax[base + (size_t)(32 + kt2) * 64] = lo;
    }
}

// ---------------------------------------------------------------------------
extern "C" void kernel_launch(void* const* d_in, const int* in_sizes, int n_in,
                              void* d_out, int out_size, void* d_ws, size_t ws_size,
                              hipStream_t stream)
{
    const float* query = (const float*)d_in[0];
    const float* key   = (const float*)d_in[1];
    const float* value = (const float*)d_in[2];
    const float* Wq = (const float*)d_in[3];
    const float* bq = (const float*)d_in[4];
    const float* Wk = (const float*)d_in[5];
    const float* bk = (const float*)d_in[6];
    const float* Wv = (const float*)d_in[7];
    const float* bv = (const float*)d_in[8];
    const float* Ww = (const float*)d_in[9];
    const float* bw = (const float*)d_in[10];
    const float* Wu = (const float*)d_in[11];
    const float* bu = (const float*)d_in[12];
    const float* vv = (const float*)d_in[13];
    const float* Wo = (const float*)d_in[14];
    const float* bo = (const float*)d_in[15];

    float* out_x    = (float*)d_out;                 // [2,384,512]
    float* out_attn = out_x + (size_t)MROWS * HID;   // [2,8,384,384]

    float* ws  = (float*)d_ws;
    float* bqe = ws;                 // 512
    float* bke = bqe + 512;          // 512
    float* vv2 = bke + 512;          // 64
    float* EqB = vv2 + 64;           // 393216
    float* Ek4 = EqB + 393216;       // 393216 (transposed-packed)
    float* Vw  = Ek4 + 393216;       // 393216

    s8v* packs = (s8v*)(Vw + 393216);        // 16B-aligned
    s8v* Aq = packs;                          // APACK_S8 each
    s8v* Ak = Aq + APACK_S8;
    s8v* Av = Ak + APACK_S8;
    s8v* Ax = Av + APACK_S8;
    s8v* Bq = Ax + APACK_S8;                  // BPACK_S8 each
    s8v* Bk = Bq + BPACK_S8;
    s8v* Bv = Bk + BPACK_S8;
    s8v* Bo = Bv + BPACK_S8;

    pack_all_kernel<<<dim3(1089), 256, 0, stream>>>(
        query, key, value,
        Wq, bq, Wk, bk, Wv, Wo, Ww, bw, Wu, bu, vv,
        Aq, Ak, Av, Bq, Bk, Bv, Bo,
        bqe, bke, vv2);
    proj3_mfma_kernel<<<dim3(24, 16, 3), 64, 0, stream>>>(Aq, Ak, Av, Bq, Bk, Bv,
                                                          bqe, bke, bv,
                                                          EqB, Ek4, Vw);
    attn_kernel<<<dim3(96, 16), 256, 0, stream>>>(EqB, Ek4, Vw, vv2, out_attn, Ax);
    out_mfma_kernel<<<dim3(24, 16), 64, 0, stream>>>(Ax, Bo, bo, out_x);
}

// Round 9
// 193.787 us; speedup vs baseline: 1.1230x; 1.1230x over previous
//
#include <hip/hip_runtime.h>

#define HID 512
#define HEADS 8
#define HD 64
#define BATCH 2
#define SEQ 384
#define MROWS (BATCH * SEQ)  // 768
#define KT_N 48              // k'-tiles: 1536 / 32
#define APACK_S8 (48 * KT_N * 64)   // 147456 s8-chunks per packed A (768x1536 bf16)
#define BPACK_S8 (32 * KT_N * 64)   // 98304 s8-chunks per packed B (512x1536 bf16)

// 2*log2(e): Eq = exp2(C1 * qW) == exp(2*qW)
#define C1 2.8853900817779268f
// log2(e)/8: softmax exponent scale (energy = raw/8)
#define SSCL 0.18033688011112043f

typedef __attribute__((ext_vector_type(8))) short s8v;   // 8 bf16 (4 VGPR)
typedef __attribute__((ext_vector_type(4))) float f4v;   // MFMA acc

__device__ __forceinline__ unsigned short bf16_rne(float x) {
    union { float f; unsigned u; } v; v.f = x;
    unsigned r = v.u + 0x7FFFu + ((v.u >> 16) & 1u);
    return (unsigned short)(r >> 16);
}
__device__ __forceinline__ float bf16_val(unsigned short h) {
    union { float f; unsigned u; } v; v.u = ((unsigned)h) << 16; return v.f;
}

// ---------------------------------------------------------------------------
// Pack A [768x512 f32] -> A' [768 x 1536 bf16] = [Ah | Ah | Al] in MFMA swizzle
// ---------------------------------------------------------------------------
__device__ __forceinline__ void pack_a_one(const float* __restrict__ src,
                                           s8v* __restrict__ dst, int rem)
{
    int g = rem & 63, m = rem >> 6;           // c = 8g .. 8g+7
    const float4* sp = (const float4*)(src + (size_t)m * HID + g * 8);
    float4 v0 = sp[0], v1 = sp[1];
    float vals[8] = {v0.x, v0.y, v0.z, v0.w, v1.x, v1.y, v1.z, v1.w};
    s8v hi, lo;
    #pragma unroll
    for (int j = 0; j < 8; ++j) {
        unsigned short h = bf16_rne(vals[j]);
        hi[j] = (short)h;
        lo[j] = (short)bf16_rne(vals[j] - bf16_val(h));
    }
    int mt = m >> 4, kt = g >> 2;
    int lanei = (m & 15) | ((g & 3) << 4);
    size_t base = ((size_t)mt * KT_N) * 64 + lanei;
    dst[base + (size_t)kt * 64]        = hi;  // sec1: Ah (x Bh)
    dst[base + (size_t)(16 + kt) * 64] = hi;  // sec2: Ah (x Bl)
    dst[base + (size_t)(32 + kt) * 64] = lo;  // sec3: Al (x Bh)
}

// ---------------------------------------------------------------------------
// Pack W [512x512 f32, (k,n)] -> B' [Bh | Bl | Bh] in MFMA swizzle
// ---------------------------------------------------------------------------
__device__ __forceinline__ void pack_w_store(s8v* __restrict__ dst,
                                             const float vals[8], int kg, int n)
{
    s8v hi, lo;
    #pragma unroll
    for (int j = 0; j < 8; ++j) {
        unsigned short h = bf16_rne(vals[j]);
        hi[j] = (short)h;
        lo[j] = (short)bf16_rne(vals[j] - bf16_val(h));
    }
    int nt = n >> 4, kt = kg >> 2;
    int lanei = (n & 15) | ((kg & 3) << 4);
    size_t base = ((size_t)nt * KT_N) * 64 + lanei;
    dst[base + (size_t)kt * 64]        = hi;  // sec1: Bh
    dst[base + (size_t)(16 + kt) * 64] = lo;  // sec2: Bl
    dst[base + (size_t)(32 + kt) * 64] = hi;  // sec3: Bh
}

__device__ __forceinline__ void pack_w_one(const float* __restrict__ W,
                                           s8v* __restrict__ dst, int rem)
{
    int kg = rem >> 9, n = rem & 511;         // k = 8kg .. 8kg+7
    float vals[8];
    #pragma unroll
    for (int j = 0; j < 8; ++j)
        vals[j] = W[(size_t)(kg * 8 + j) * HID + n];   // coalesced across n
    pack_w_store(dst, vals, kg, n);
}

// fold Wbig(512x512) @ blockdiag(Wsmall 64x64) on the fly, then pack
__device__ __forceinline__ void fold_pack_w_one(const float* __restrict__ Wbig,
                                                const float* __restrict__ Wsmall,
                                                s8v* __restrict__ dst, int rem)
{
    int kg = __builtin_amdgcn_readfirstlane(rem >> 9);
    int n  = rem & 511;
    int h  = __builtin_amdgcn_readfirstlane(n >> 6);
    int d  = n & 63;
    const float* wr = Wbig + (size_t)(kg * 8) * HID + h * HD;
    float acc[8] = {0.f, 0.f, 0.f, 0.f, 0.f, 0.f, 0.f, 0.f};
    #pragma unroll 8
    for (int t = 0; t < 64; ++t) {
        float wv = Wsmall[t * 64 + d];      // coalesced across lanes
        #pragma unroll
        for (int j = 0; j < 8; ++j)
            acc[j] = fmaf(wr[(size_t)j * HID + t], wv, acc[j]);  // uniform
    }
    pack_w_store(dst, acc, kg, n);
}

// ---------------------------------------------------------------------------
// ONE launch for all prep+pack work (no internal dependencies):
// [0,576): A packs q,k,v | [576,704): Wv | [704,832): Wo
// [832,960): fold(Wq,Ww) | [960,1088): fold(Wk,Wu) | [1088]: biases + vv2
// ---------------------------------------------------------------------------
__global__ __launch_bounds__(256) void pack_all_kernel(
    const float* __restrict__ q, const float* __restrict__ k, const float* __restrict__ v,
    const float* __restrict__ Wq, const float* __restrict__ bq,
    const float* __restrict__ Wk, const float* __restrict__ bk,
    const float* __restrict__ Wv, const float* __restrict__ Wo,
    const float* __restrict__ Ww, const float* __restrict__ bw,
    const float* __restrict__ Wu, const float* __restrict__ bu,
    const float* __restrict__ vv,
    s8v* __restrict__ Aq, s8v* __restrict__ Ak, s8v* __restrict__ Av,
    s8v* __restrict__ Bq, s8v* __restrict__ Bk, s8v* __restrict__ Bv, s8v* __restrict__ Bo,
    float* __restrict__ bqe, float* __restrict__ bke, float* __restrict__ vv2)
{
    int bx = blockIdx.x, tid = threadIdx.x;
    if (bx < 576) {
        int p = bx / 192;
        int rem = (bx % 192) * 256 + tid;
        const float* src = (p == 0) ? q : (p == 1) ? k : v;
        s8v* dst = (p == 0) ? Aq : (p == 1) ? Ak : Av;
        pack_a_one(src, dst, rem);
    } else if (bx < 704) {
        pack_w_one(Wv, Bv, (bx - 576) * 256 + tid);
    } else if (bx < 832) {
        pack_w_one(Wo, Bo, (bx - 704) * 256 + tid);
    } else if (bx < 960) {
        fold_pack_w_one(Wq, Ww, Bq, (bx - 832) * 256 + tid);
    } else if (bx < 1088) {
        fold_pack_w_one(Wk, Wu, Bk, (bx - 960) * 256 + tid);
    } else {
        for (int i = tid; i < 1088; i += 256) {
            if (i < 512) {
                int h = i >> 6, j = i & 63;
                float s = bw[j];
                for (int t = 0; t < 64; ++t) s = fmaf(bq[h * 64 + t], Ww[t * 64 + j], s);
                bqe[i] = s;
            } else if (i < 1024) {
                int n = i - 512, h = n >> 6, j = n & 63;
                float s = bu[j];
                for (int t = 0; t < 64; ++t) s = fmaf(bk[h * 64 + t], Wu[t * 64 + j], s);
                bke[n] = s;
            } else {
                vv2[i - 1024] = -2.0f * vv[i - 1024];
            }
        }
    }
}

// ---------------------------------------------------------------------------
// MFMA GEMM: one WAVE per block (64 thr), 32x32 tile (2x2 MFMA 16x16x32).
// No LDS, no barriers; fragments loaded coalesced b128 from swizzled packs.
// MODE 0: plain  MODE 1: exp2(C1*y)  MODE 2: exp2 + transposed-packed Ek4
// ---------------------------------------------------------------------------
template <int MODE>
__device__ __forceinline__ void mfma_gemm_body(
    const s8v* __restrict__ Ap, const s8v* __restrict__ Bp,
    const float* __restrict__ bias, float* __restrict__ out,
    int mt0, int nt0)
{
    int lane = threadIdx.x & 63;

    const s8v* a0p = Ap + (size_t)(mt0 * KT_N) * 64 + lane;
    const s8v* a1p = a0p + (size_t)KT_N * 64;
    const s8v* b0p = Bp + (size_t)(nt0 * KT_N) * 64 + lane;
    const s8v* b1p = b0p + (size_t)KT_N * 64;

    f4v acc00 = {0.f, 0.f, 0.f, 0.f};
    f4v acc01 = {0.f, 0.f, 0.f, 0.f};
    f4v acc10 = {0.f, 0.f, 0.f, 0.f};
    f4v acc11 = {0.f, 0.f, 0.f, 0.f};

    s8v xa0 = a0p[0], xa1 = a1p[0], xb0 = b0p[0], xb1 = b1p[0];
    #pragma unroll 1
    for (int kt = 0; kt < KT_N; kt += 2) {
        int o1 = (kt + 1) * 64;
        s8v ya0 = a0p[o1], ya1 = a1p[o1], yb0 = b0p[o1], yb1 = b1p[o1];
        acc00 = __builtin_amdgcn_mfma_f32_16x16x32_bf16(xa0, xb0, acc00, 0, 0, 0);
        acc01 = __builtin_amdgcn_mfma_f32_16x16x32_bf16(xa0, xb1, acc01, 0, 0, 0);
        acc10 = __builtin_amdgcn_mfma_f32_16x16x32_bf16(xa1, xb0, acc10, 0, 0, 0);
        acc11 = __builtin_amdgcn_mfma_f32_16x16x32_bf16(xa1, xb1, acc11, 0, 0, 0);
        int o2 = (kt + 2 < KT_N) ? (kt + 2) * 64 : 0;   // tail wrap: harmless load
        xa0 = a0p[o2]; xa1 = a1p[o2]; xb0 = b0p[o2]; xb1 = b1p[o2];
        acc00 = __builtin_amdgcn_mfma_f32_16x16x32_bf16(ya0, yb0, acc00, 0, 0, 0);
        acc01 = __builtin_amdgcn_mfma_f32_16x16x32_bf16(ya0, yb1, acc01, 0, 0, 0);
        acc10 = __builtin_amdgcn_mfma_f32_16x16x32_bf16(ya1, yb0, acc10, 0, 0, 0);
        acc11 = __builtin_amdgcn_mfma_f32_16x16x32_bf16(ya1, yb1, acc11, 0, 0, 0);
    }

    // Epilogue. C/D layout: row = quad*4 + reg, col = lane&15.
    int quad = lane >> 4, c16 = lane & 15;
    int col0 = nt0 * 16 + c16, col1 = col0 + 16;
    float bias0 = bias[col0], bias1 = bias[col1];
    int row0 = mt0 * 16 + quad * 4;
    int row1 = row0 + 16;

    #pragma unroll
    for (int r = 0; r < 4; ++r) {
        float y;
        #define WR(ROW, COL, Y)                                                     \
        {                                                                           \
            float yy = (Y);                                                         \
            if (MODE != 0) yy = __builtin_amdgcn_exp2f(C1 * yy);                    \
            if (MODE == 2) {                                                        \
                int b2 = (ROW) / SEQ, kk = (ROW) - b2 * SEQ;                        \
                int hh = (COL) >> 6, dd = (COL) & 63;                               \
                out[(((size_t)((b2 * 8 + hh) * 16 + (dd >> 2)) * SEQ + kk) << 2)    \
                    + (dd & 3)] = yy;                                               \
            } else {                                                                \
                out[(size_t)(ROW) * HID + (COL)] = yy;                              \
            }                                                                       \
        }
        y = acc00[r] + bias0; WR(row0 + r, col0, y);
        y = acc01[r] + bias1; WR(row0 + r, col1, y);
        y = acc10[r] + bias0; WR(row1 + r, col0, y);
        y = acc11[r] + bias1; WR(row1 + r, col1, y);
        #undef WR
    }
}

__global__ __launch_bounds__(64) void proj3_mfma_kernel(
    const s8v* __restrict__ Aq, const s8v* __restrict__ Ak, const s8v* __restrict__ Av,
    const s8v* __restrict__ Bq, const s8v* __restrict__ Bk, const s8v* __restrict__ Bv,
    const float* __restrict__ bqe, const float* __restrict__ bke, const float* __restrict__ bv,
    float* __restrict__ Eq, float* __restrict__ Ek4, float* __restrict__ V)
{
    int p = blockIdx.z;
    int mt0 = blockIdx.x * 2, nt0 = blockIdx.y * 2;
    if (p == 0)      mfma_gemm_body<1>(Aq, Bq, bqe, Eq,  mt0, nt0);
    else if (p == 1) mfma_gemm_body<2>(Ak, Bk, bke, Ek4, mt0, nt0);
    else             mfma_gemm_body<0>(Av, Bv, bv,  V,   mt0, nt0);
}

__global__ __launch_bounds__(64) void out_mfma_kernel(
    const s8v* __restrict__ Ax, const s8v* __restrict__ Bo,
    const float* __restrict__ bo, float* __restrict__ out)
{
    mfma_gemm_body<0>(Ax, Bo, bo, out, blockIdx.x * 2, blockIdx.y * 2);
}

// ---------------------------------------------------------------------------
// attention (R7 structure + cross-chunk rotating prefetch):
// 2 q-rows per wave, grid (48,16) = 768 blocks = 3 blocks/CU, no barriers.
// Eq/vv2 wave-uniform -> scalar; Ek4 coalesced b128, prefetch flows across
// c-chunk boundaries (only 1 cold load per wave instead of 4).
// Epilogue packs X directly into Ax (bf16 3-term MFMA swizzle).
// ---------------------------------------------------------------------------
__global__ __launch_bounds__(256, 4) void attn_kernel(
    const float* __restrict__ Eq, const float* __restrict__ Ek4,
    const float* __restrict__ V, const float* __restrict__ vv2,
    float* __restrict__ attnOut, s8v* __restrict__ Ax)
{
    __shared__ float2 aP[4][SEQ];

    int bh = blockIdx.y;
    int b = bh >> 3, h = bh & 7;
    int tid = threadIdx.x;
    int wave = __builtin_amdgcn_readfirstlane(tid >> 6);
    int lane = tid & 63;
    int q0 = blockIdx.x * 8 + wave * 2, q1 = q0 + 1;

    const float* eq0 = Eq + (size_t)(b * SEQ + q0) * HID + h * HD;  // uniform
    const float* eq1 = eq0 + HID;
    const float4* ekbase = (const float4*)Ek4 + (size_t)bh * 16 * SEQ + lane;

    float e0[6], e1[6];
    #pragma unroll
    for (int t = 0; t < 6; ++t) { e0[t] = 0.f; e1[t] = 0.f; }

    // rotating prefetch primed once; flows across c-chunk boundaries
    float4 k0 = ekbase[0], k1 = ekbase[SEQ], k2 = ekbase[2 * SEQ], k3 = ekbase[3 * SEQ];
    #pragma unroll 1
    for (int c = 0; c < 4; ++c) {
        float g0[16], g1[16], w[16];
        #pragma unroll
        for (int j = 0; j < 16; ++j) {
            g0[j] = eq0[c * 16 + j];   // wave-uniform -> s_load
            g1[j] = eq1[c * 16 + j];
            w[j]  = vv2[c * 16 + j];
        }
        #pragma unroll
        for (int kt = 0; kt < 6; ++kt) {
            float4 n0 = k0, n1 = k1, n2 = k2, n3 = k3;
            if (!(c == 3 && kt == 5)) {
                const float4* np = (kt < 5) ? (ekbase + c * 4 * SEQ + (kt + 1) * 64)
                                            : (ekbase + (c + 1) * 4 * SEQ);
                n0 = np[0]; n1 = np[SEQ]; n2 = np[2 * SEQ]; n3 = np[3 * SEQ];
            }
            float r0 = e0[kt], r1 = e1[kt];
            #define EN(J, KV)                                                      \
            {                                                                      \
                float t0 = __builtin_amdgcn_rcpf(fmaf(g0[J], (KV), 1.f));          \
                float t1 = __builtin_amdgcn_rcpf(fmaf(g1[J], (KV), 1.f));          \
                r0 = fmaf(w[J], t0, r0);                                           \
                r1 = fmaf(w[J], t1, r1);                                           \
            }
            EN(0,  k0.x) EN(1,  k0.y) EN(2,  k0.z) EN(3,  k0.w)
            EN(4,  k1.x) EN(5,  k1.y) EN(6,  k1.z) EN(7,  k1.w)
            EN(8,  k2.x) EN(9,  k2.y) EN(10, k2.z) EN(11, k2.w)
            EN(12, k3.x) EN(13, k3.y) EN(14, k3.z) EN(15, k3.w)
            #undef EN
            e0[kt] = r0; e1[kt] = r1;
            k0 = n0; k1 = n1; k2 = n2; k3 = n3;
        }
    }

    // softmax over k (384 = 6 tiles x 64 lanes)
    float m0 = e0[0], m1 = e1[0];
    #pragma unroll
    for (int t = 1; t < 6; ++t) { m0 = fmaxf(m0, e0[t]); m1 = fmaxf(m1, e1[t]); }
    #pragma unroll
    for (int off = 1; off < 64; off <<= 1) {
        m0 = fmaxf(m0, __shfl_xor(m0, off));
        m1 = fmaxf(m1, __shfl_xor(m1, off));
    }
    float a0[6], a1[6], s0 = 0.f, s1 = 0.f;
    #pragma unroll
    for (int t = 0; t < 6; ++t) {
        a0[t] = __builtin_amdgcn_exp2f((e0[t] - m0) * SSCL); s0 += a0[t];
        a1[t] = __builtin_amdgcn_exp2f((e1[t] - m1) * SSCL); s1 += a1[t];
    }
    #pragma unroll
    for (int off = 1; off < 64; off <<= 1) {
        s0 += __shfl_xor(s0, off);
        s1 += __shfl_xor(s1, off);
    }
    float z0 = __builtin_amdgcn_rcpf(s0), z1 = __builtin_amdgcn_rcpf(s1);

    size_t abase = (size_t)bh * SEQ * SEQ + (size_t)q0 * SEQ;
    #pragma unroll
    for (int t = 0; t < 6; ++t) {
        float v0 = a0[t] * z0, v1 = a1[t] * z1;
        attnOut[abase + t * 64 + lane] = v0;
        attnOut[abase + SEQ + t * 64 + lane] = v1;
        aP[wave][t * 64 + lane] = make_float2(v0, v1);
    }
    // no barrier: aP[wave] written and read by the same wave

    // attn @ V: lane = ko*16 + d4p; 4 k-phases, float4 over d, 2 q rows
    int ko = lane >> 4, d4p = lane & 15;
    const float4* vb = (const float4*)&V[(size_t)b * SEQ * HID + h * HD + d4p * 4];
    float4 x0 = make_float4(0.f, 0.f, 0.f, 0.f);
    float4 x1 = make_float4(0.f, 0.f, 0.f, 0.f);
    #pragma unroll 8
    for (int k = ko; k < SEQ; k += 4) {
        float4 v = vb[(size_t)k * (HID / 4)];
        float2 a = aP[wave][k];
        x0.x = fmaf(a.x, v.x, x0.x); x0.y = fmaf(a.x, v.y, x0.y);
        x0.z = fmaf(a.x, v.z, x0.z); x0.w = fmaf(a.x, v.w, x0.w);
        x1.x = fmaf(a.y, v.x, x1.x); x1.y = fmaf(a.y, v.y, x1.y);
        x1.z = fmaf(a.y, v.z, x1.z); x1.w = fmaf(a.y, v.w, x1.w);
    }
    #pragma unroll
    for (int off = 16; off < 64; off <<= 1) {
        x0.x += __shfl_xor(x0.x, off); x0.y += __shfl_xor(x0.y, off);
        x0.z += __shfl_xor(x0.z, off); x0.w += __shfl_xor(x0.w, off);
        x1.x += __shfl_xor(x1.x, off); x1.y += __shfl_xor(x1.y, off);
        x1.z += __shfl_xor(x1.z, off); x1.w += __shfl_xor(x1.w, off);
    }

    // Pack X rows q0/q1 (this head's 64 cols) straight into Ax.
    // Lanes 0..15 hold the full row as float4; chunk u (8 floats) = lanes {2u,2u+1}.
    if (ko == 0) {
        float4 p0, p1;
        p0.x = __shfl_xor(x0.x, 1); p0.y = __shfl_xor(x0.y, 1);
        p0.z = __shfl_xor(x0.z, 1); p0.w = __shfl_xor(x0.w, 1);
        p1.x = __shfl_xor(x1.x, 1); p1.y = __shfl_xor(x1.y, 1);
        p1.z = __shfl_xor(x1.z, 1); p1.w = __shfl_xor(x1.w, 1);
        float vals[8];
        int row;
        if ((lane & 1) == 0) {
            vals[0] = x0.x; vals[1] = x0.y; vals[2] = x0.z; vals[3] = x0.w;
            vals[4] = p0.x; vals[5] = p0.y; vals[6] = p0.z; vals[7] = p0.w;
            row = b * SEQ + q0;
        } else {
            vals[0] = p1.x; vals[1] = p1.y; vals[2] = p1.z; vals[3] = p1.w;
            vals[4] = x1.x; vals[5] = x1.y; vals[6] = x1.z; vals[7] = x1.w;
            row = b * SEQ + q1;
        }
        int g = h * 8 + (lane >> 1);   // global 8-col group
        s8v hi, lo;
        #pragma unroll
        for (int j = 0; j < 8; ++j) {
            unsigned short hh = bf16_rne(vals[j]);
            hi[j] = (short)hh;
            lo[j] = (short)bf16_rne(vals[j] - bf16_val(hh));
        }
        int mt = row >> 4, kt2 = g >> 2;
        int lanei = (row & 15) | ((g & 3) << 4);
        size_t base = ((size_t)mt * KT_N) * 64 + lanei;
        Ax[base + (size_t)kt2 * 64]        = hi;
        Ax[base + (size_t)(16 + kt2) * 64] = hi;
        Ax[base + (size_t)(32 + kt2) * 64] = lo;
    }
}

// ---------------------------------------------------------------------------
extern "C" void kernel_launch(void* const* d_in, const int* in_sizes, int n_in,
                              void* d_out, int out_size, void* d_ws, size_t ws_size,
                              hipStream_t stream)
{
    const float* query = (const float*)d_in[0];
    const float* key   = (const float*)d_in[1];
    const float* value = (const float*)d_in[2];
    const float* Wq = (const float*)d_in[3];
    const float* bq = (const float*)d_in[4];
    const float* Wk = (const float*)d_in[5];
    const float* bk = (const float*)d_in[6];
    const float* Wv = (const float*)d_in[7];
    const float* bv = (const float*)d_in[8];
    const float* Ww = (const float*)d_in[9];
    const float* bw = (const float*)d_in[10];
    const float* Wu = (const float*)d_in[11];
    const float* bu = (const float*)d_in[12];
    const float* vv = (const float*)d_in[13];
    const float* Wo = (const float*)d_in[14];
    const float* bo = (const float*)d_in[15];

    float* out_x    = (float*)d_out;                 // [2,384,512]
    float* out_attn = out_x + (size_t)MROWS * HID;   // [2,8,384,384]

    float* ws  = (float*)d_ws;
    float* bqe = ws;                 // 512
    float* bke = bqe + 512;          // 512
    float* vv2 = bke + 512;          // 64
    float* EqB = vv2 + 64;           // 393216
    float* Ek4 = EqB + 393216;       // 393216 (transposed-packed)
    float* Vw  = Ek4 + 393216;       // 393216

    s8v* packs = (s8v*)(Vw + 393216);        // 16B-aligned
    s8v* Aq = packs;                          // APACK_S8 each
    s8v* Ak = Aq + APACK_S8;
    s8v* Av = Ak + APACK_S8;
    s8v* Ax = Av + APACK_S8;
    s8v* Bq = Ax + APACK_S8;                  // BPACK_S8 each
    s8v* Bk = Bq + BPACK_S8;
    s8v* Bv = Bk + BPACK_S8;
    s8v* Bo = Bv + BPACK_S8;

    pack_all_kernel<<<dim3(1089), 256, 0, stream>>>(
        query, key, value,
        Wq, bq, Wk, bk, Wv, Wo, Ww, bw, Wu, bu, vv,
        Aq, Ak, Av, Bq, Bk, Bv, Bo,
        bqe, bke, vv2);
    proj3_mfma_kernel<<<dim3(24, 16, 3), 64, 0, stream>>>(Aq, Ak, Av, Bq, Bk, Bv,
                                                          bqe, bke, bv,
                                                          EqB, Ek4, Vw);
    attn_kernel<<<dim3(48, 16), 256, 0, stream>>>(EqB, Ek4, Vw, vv2, out_attn, Ax);
    out_mfma_kernel<<<dim3(24, 16), 64, 0, stream>>>(Ax, Bo, bo, out_x);
}

// Round 10
// 144.730 us; speedup vs baseline: 1.5037x; 1.3390x over previous
//
#include <hip/hip_runtime.h>

#define HID 512
#define HEADS 8
#define HD 64
#define BATCH 2
#define SEQ 384
#define MROWS (BATCH * SEQ)  // 768
#define KT_N 48              // k'-tiles: 1536 / 32
#define APACK_S8 (48 * KT_N * 64)   // 147456 s8-chunks per packed A (768x1536 bf16)
#define BPACK_S8 (32 * KT_N * 64)   // 98304 s8-chunks per packed B (512x1536 bf16)

// 2*log2(e): Eq = exp2(C1 * qW) == exp(2*qW)
#define C1 2.8853900817779268f
// log2(e)/8: softmax exponent scale (energy = raw/8)
#define SSCL 0.18033688011112043f

typedef __attribute__((ext_vector_type(8))) short s8v;   // 8 bf16 (4 VGPR)
typedef __attribute__((ext_vector_type(4))) float f4v;   // MFMA acc

__device__ __forceinline__ unsigned short bf16_rne(float x) {
    union { float f; unsigned u; } v; v.f = x;
    unsigned r = v.u + 0x7FFFu + ((v.u >> 16) & 1u);
    return (unsigned short)(r >> 16);
}
__device__ __forceinline__ float bf16_val(unsigned short h) {
    union { float f; unsigned u; } v; v.u = ((unsigned)h) << 16; return v.f;
}

// ---------------------------------------------------------------------------
// Pack A [768x512 f32] -> A' [768 x 1536 bf16] = [Ah | Ah | Al] in MFMA swizzle
// ---------------------------------------------------------------------------
__device__ __forceinline__ void pack_a_one(const float* __restrict__ src,
                                           s8v* __restrict__ dst, int rem)
{
    int g = rem & 63, m = rem >> 6;           // c = 8g .. 8g+7
    const float4* sp = (const float4*)(src + (size_t)m * HID + g * 8);
    float4 v0 = sp[0], v1 = sp[1];
    float vals[8] = {v0.x, v0.y, v0.z, v0.w, v1.x, v1.y, v1.z, v1.w};
    s8v hi, lo;
    #pragma unroll
    for (int j = 0; j < 8; ++j) {
        unsigned short h = bf16_rne(vals[j]);
        hi[j] = (short)h;
        lo[j] = (short)bf16_rne(vals[j] - bf16_val(h));
    }
    int mt = m >> 4, kt = g >> 2;
    int lanei = (m & 15) | ((g & 3) << 4);
    size_t base = ((size_t)mt * KT_N) * 64 + lanei;
    dst[base + (size_t)kt * 64]        = hi;  // sec1: Ah (x Bh)
    dst[base + (size_t)(16 + kt) * 64] = hi;  // sec2: Ah (x Bl)
    dst[base + (size_t)(32 + kt) * 64] = lo;  // sec3: Al (x Bh)
}

// ---------------------------------------------------------------------------
// Pack W [512x512 f32, (k,n)] -> B' [Bh | Bl | Bh] in MFMA swizzle
// ---------------------------------------------------------------------------
__device__ __forceinline__ void pack_w_store(s8v* __restrict__ dst,
                                             const float vals[8], int kg, int n)
{
    s8v hi, lo;
    #pragma unroll
    for (int j = 0; j < 8; ++j) {
        unsigned short h = bf16_rne(vals[j]);
        hi[j] = (short)h;
        lo[j] = (short)bf16_rne(vals[j] - bf16_val(h));
    }
    int nt = n >> 4, kt = kg >> 2;
    int lanei = (n & 15) | ((kg & 3) << 4);
    size_t base = ((size_t)nt * KT_N) * 64 + lanei;
    dst[base + (size_t)kt * 64]        = hi;  // sec1: Bh
    dst[base + (size_t)(16 + kt) * 64] = lo;  // sec2: Bl
    dst[base + (size_t)(32 + kt) * 64] = hi;  // sec3: Bh
}

__device__ __forceinline__ void pack_w_one(const float* __restrict__ W,
                                           s8v* __restrict__ dst, int rem)
{
    int kg = rem >> 9, n = rem & 511;         // k = 8kg .. 8kg+7
    float vals[8];
    #pragma unroll
    for (int j = 0; j < 8; ++j)
        vals[j] = W[(size_t)(kg * 8 + j) * HID + n];   // coalesced across n
    pack_w_store(dst, vals, kg, n);
}

// fold Wbig(512x512) @ blockdiag(Wsmall 64x64) on the fly, then pack
__device__ __forceinline__ void fold_pack_w_one(const float* __restrict__ Wbig,
                                                const float* __restrict__ Wsmall,
                                                s8v* __restrict__ dst, int rem)
{
    int kg = __builtin_amdgcn_readfirstlane(rem >> 9);
    int n  = rem & 511;
    int h  = __builtin_amdgcn_readfirstlane(n >> 6);
    int d  = n & 63;
    const float* wr = Wbig + (size_t)(kg * 8) * HID + h * HD;
    float acc[8] = {0.f, 0.f, 0.f, 0.f, 0.f, 0.f, 0.f, 0.f};
    #pragma unroll 8
    for (int t = 0; t < 64; ++t) {
        float wv = Wsmall[t * 64 + d];      // coalesced across lanes
        #pragma unroll
        for (int j = 0; j < 8; ++j)
            acc[j] = fmaf(wr[(size_t)j * HID + t], wv, acc[j]);  // uniform
    }
    pack_w_store(dst, acc, kg, n);
}

// ---------------------------------------------------------------------------
// ONE launch for all prep+pack work (no internal dependencies):
// [0,576): A packs q,k,v | [576,704): Wv | [704,832): Wo
// [832,960): fold(Wq,Ww) | [960,1088): fold(Wk,Wu) | [1088]: biases + vv2
// ---------------------------------------------------------------------------
__global__ __launch_bounds__(256) void pack_all_kernel(
    const float* __restrict__ q, const float* __restrict__ k, const float* __restrict__ v,
    const float* __restrict__ Wq, const float* __restrict__ bq,
    const float* __restrict__ Wk, const float* __restrict__ bk,
    const float* __restrict__ Wv, const float* __restrict__ Wo,
    const float* __restrict__ Ww, const float* __restrict__ bw,
    const float* __restrict__ Wu, const float* __restrict__ bu,
    const float* __restrict__ vv,
    s8v* __restrict__ Aq, s8v* __restrict__ Ak, s8v* __restrict__ Av,
    s8v* __restrict__ Bq, s8v* __restrict__ Bk, s8v* __restrict__ Bv, s8v* __restrict__ Bo,
    float* __restrict__ bqe, float* __restrict__ bke, float* __restrict__ vv2)
{
    int bx = blockIdx.x, tid = threadIdx.x;
    if (bx < 576) {
        int p = bx / 192;
        int rem = (bx % 192) * 256 + tid;
        const float* src = (p == 0) ? q : (p == 1) ? k : v;
        s8v* dst = (p == 0) ? Aq : (p == 1) ? Ak : Av;
        pack_a_one(src, dst, rem);
    } else if (bx < 704) {
        pack_w_one(Wv, Bv, (bx - 576) * 256 + tid);
    } else if (bx < 832) {
        pack_w_one(Wo, Bo, (bx - 704) * 256 + tid);
    } else if (bx < 960) {
        fold_pack_w_one(Wq, Ww, Bq, (bx - 832) * 256 + tid);
    } else if (bx < 1088) {
        fold_pack_w_one(Wk, Wu, Bk, (bx - 960) * 256 + tid);
    } else {
        for (int i = tid; i < 1088; i += 256) {
            if (i < 512) {
                int h = i >> 6, j = i & 63;
                float s = bw[j];
                for (int t = 0; t < 64; ++t) s = fmaf(bq[h * 64 + t], Ww[t * 64 + j], s);
                bqe[i] = s;
            } else if (i < 1024) {
                int n = i - 512, h = n >> 6, j = n & 63;
                float s = bu[j];
                for (int t = 0; t < 64; ++t) s = fmaf(bk[h * 64 + t], Wu[t * 64 + j], s);
                bke[n] = s;
            } else {
                vv2[i - 1024] = -2.0f * vv[i - 1024];
            }
        }
    }
}

// ---------------------------------------------------------------------------
// MFMA GEMM: one WAVE per block (64 thr), 32x32 tile (2x2 MFMA 16x16x32).
// No LDS, no barriers; fragments loaded coalesced b128 from swizzled packs.
// MODE 0: plain  MODE 1: exp2(C1*y)  MODE 2: exp2 + transposed-packed Ek4
// ---------------------------------------------------------------------------
template <int MODE>
__device__ __forceinline__ void mfma_gemm_body(
    const s8v* __restrict__ Ap, const s8v* __restrict__ Bp,
    const float* __restrict__ bias, float* __restrict__ out,
    int mt0, int nt0)
{
    int lane = threadIdx.x & 63;

    const s8v* a0p = Ap + (size_t)(mt0 * KT_N) * 64 + lane;
    const s8v* a1p = a0p + (size_t)KT_N * 64;
    const s8v* b0p = Bp + (size_t)(nt0 * KT_N) * 64 + lane;
    const s8v* b1p = b0p + (size_t)KT_N * 64;

    f4v acc00 = {0.f, 0.f, 0.f, 0.f};
    f4v acc01 = {0.f, 0.f, 0.f, 0.f};
    f4v acc10 = {0.f, 0.f, 0.f, 0.f};
    f4v acc11 = {0.f, 0.f, 0.f, 0.f};

    s8v xa0 = a0p[0], xa1 = a1p[0], xb0 = b0p[0], xb1 = b1p[0];
    #pragma unroll 1
    for (int kt = 0; kt < KT_N; kt += 2) {
        int o1 = (kt + 1) * 64;
        s8v ya0 = a0p[o1], ya1 = a1p[o1], yb0 = b0p[o1], yb1 = b1p[o1];
        acc00 = __builtin_amdgcn_mfma_f32_16x16x32_bf16(xa0, xb0, acc00, 0, 0, 0);
        acc01 = __builtin_amdgcn_mfma_f32_16x16x32_bf16(xa0, xb1, acc01, 0, 0, 0);
        acc10 = __builtin_amdgcn_mfma_f32_16x16x32_bf16(xa1, xb0, acc10, 0, 0, 0);
        acc11 = __builtin_amdgcn_mfma_f32_16x16x32_bf16(xa1, xb1, acc11, 0, 0, 0);
        int o2 = (kt + 2 < KT_N) ? (kt + 2) * 64 : 0;   // tail wrap: harmless load
        xa0 = a0p[o2]; xa1 = a1p[o2]; xb0 = b0p[o2]; xb1 = b1p[o2];
        acc00 = __builtin_amdgcn_mfma_f32_16x16x32_bf16(ya0, yb0, acc00, 0, 0, 0);
        acc01 = __builtin_amdgcn_mfma_f32_16x16x32_bf16(ya0, yb1, acc01, 0, 0, 0);
        acc10 = __builtin_amdgcn_mfma_f32_16x16x32_bf16(ya1, yb0, acc10, 0, 0, 0);
        acc11 = __builtin_amdgcn_mfma_f32_16x16x32_bf16(ya1, yb1, acc11, 0, 0, 0);
    }

    // Epilogue. C/D layout: row = quad*4 + reg, col = lane&15.
    int quad = lane >> 4, c16 = lane & 15;
    int col0 = nt0 * 16 + c16, col1 = col0 + 16;
    float bias0 = bias[col0], bias1 = bias[col1];
    int row0 = mt0 * 16 + quad * 4;
    int row1 = row0 + 16;

    #pragma unroll
    for (int r = 0; r < 4; ++r) {
        float y;
        #define WR(ROW, COL, Y)                                                     \
        {                                                                           \
            float yy = (Y);                                                         \
            if (MODE != 0) yy = __builtin_amdgcn_exp2f(C1 * yy);                    \
            if (MODE == 2) {                                                        \
                int b2 = (ROW) / SEQ, kk = (ROW) - b2 * SEQ;                        \
                int hh = (COL) >> 6, dd = (COL) & 63;                               \
                out[(((size_t)((b2 * 8 + hh) * 16 + (dd >> 2)) * SEQ + kk) << 2)    \
                    + (dd & 3)] = yy;                                               \
            } else {                                                                \
                out[(size_t)(ROW) * HID + (COL)] = yy;                              \
            }                                                                       \
        }
        y = acc00[r] + bias0; WR(row0 + r, col0, y);
        y = acc01[r] + bias1; WR(row0 + r, col1, y);
        y = acc10[r] + bias0; WR(row1 + r, col0, y);
        y = acc11[r] + bias1; WR(row1 + r, col1, y);
        #undef WR
    }
}

__global__ __launch_bounds__(64) void proj3_mfma_kernel(
    const s8v* __restrict__ Aq, const s8v* __restrict__ Ak, const s8v* __restrict__ Av,
    const s8v* __restrict__ Bq, const s8v* __restrict__ Bk, const s8v* __restrict__ Bv,
    const float* __restrict__ bqe, const float* __restrict__ bke, const float* __restrict__ bv,
    float* __restrict__ Eq, float* __restrict__ Ek4, float* __restrict__ V)
{
    int p = blockIdx.z;
    int mt0 = blockIdx.x * 2, nt0 = blockIdx.y * 2;
    if (p == 0)      mfma_gemm_body<1>(Aq, Bq, bqe, Eq,  mt0, nt0);
    else if (p == 1) mfma_gemm_body<2>(Ak, Bk, bke, Ek4, mt0, nt0);
    else             mfma_gemm_body<0>(Av, Bv, bv,  V,   mt0, nt0);
}

__global__ __launch_bounds__(64) void out_mfma_kernel(
    const s8v* __restrict__ Ax, const s8v* __restrict__ Bo,
    const float* __restrict__ bo, float* __restrict__ out)
{
    mfma_gemm_body<0>(Ax, Bo, bo, out, blockIdx.x * 2, blockIdx.y * 2);
}

// ---------------------------------------------------------------------------
// attention (R7 structure verbatim + XCD-aware 1-D block swizzle):
// 2 q-rows per wave, 768 blocks = 3 blocks/CU, no barriers.
// Swizzle: xcd = blk & 7 (round-robin dispatch assumption); each XCD handles
// exactly 2 bh slices -> ~8x less per-XCD L2 fetch of Ek4/V. Perf-only.
// Eq/vv2 wave-uniform -> scalar; Ek4 coalesced b128, per-chunk prefetch.
// Epilogue packs X directly into Ax (bf16 3-term MFMA swizzle).
// ---------------------------------------------------------------------------
__global__ __launch_bounds__(256, 4) void attn_kernel(
    const float* __restrict__ Eq, const float* __restrict__ Ek4,
    const float* __restrict__ V, const float* __restrict__ vv2,
    float* __restrict__ attnOut, s8v* __restrict__ Ax)
{
    __shared__ float2 aP[4][SEQ];

    int blk = blockIdx.x;
    int xcd = blk & 7, slot = blk >> 3;       // slot in [0,96)
    int part = slot / 48, qblk = slot % 48;
    int bh = xcd * 2 + part;
    int b = bh >> 3, h = bh & 7;
    int tid = threadIdx.x;
    int wave = __builtin_amdgcn_readfirstlane(tid >> 6);
    int lane = tid & 63;
    int q0 = qblk * 8 + wave * 2, q1 = q0 + 1;

    const float* eq0 = Eq + (size_t)(b * SEQ + q0) * HID + h * HD;  // uniform
    const float* eq1 = eq0 + HID;
    const float4* ekbase = (const float4*)Ek4 + (size_t)bh * 16 * SEQ + lane;

    float e0[6], e1[6];
    #pragma unroll
    for (int t = 0; t < 6; ++t) { e0[t] = 0.f; e1[t] = 0.f; }

    #pragma unroll 1
    for (int c = 0; c < 4; ++c) {
        float g0[16], g1[16], w[16];
        #pragma unroll
        for (int j = 0; j < 16; ++j) {
            g0[j] = eq0[c * 16 + j];   // wave-uniform -> s_load
            g1[j] = eq1[c * 16 + j];
            w[j]  = vv2[c * 16 + j];
        }
        const float4* ekc = ekbase + (size_t)c * 4 * SEQ;
        float4 k0 = ekc[0 * SEQ], k1 = ekc[1 * SEQ];
        float4 k2 = ekc[2 * SEQ], k3 = ekc[3 * SEQ];
        #pragma unroll
        for (int kt = 0; kt < 6; ++kt) {
            float4 n0, n1, n2, n3;
            if (kt < 5) {
                const float4* np = ekc + (kt + 1) * 64;
                n0 = np[0 * SEQ]; n1 = np[1 * SEQ];
                n2 = np[2 * SEQ]; n3 = np[3 * SEQ];
            }
            float r0 = e0[kt], r1 = e1[kt];
            #define EN(J, KV)                                                      \
            {                                                                      \
                float t0 = __builtin_amdgcn_rcpf(fmaf(g0[J], (KV), 1.f));          \
                float t1 = __builtin_amdgcn_rcpf(fmaf(g1[J], (KV), 1.f));          \
                r0 = fmaf(w[J], t0, r0);                                           \
                r1 = fmaf(w[J], t1, r1);                                           \
            }
            EN(0,  k0.x) EN(1,  k0.y) EN(2,  k0.z) EN(3,  k0.w)
            EN(4,  k1.x) EN(5,  k1.y) EN(6,  k1.z) EN(7,  k1.w)
            EN(8,  k2.x) EN(9,  k2.y) EN(10, k2.z) EN(11, k2.w)
            EN(12, k3.x) EN(13, k3.y) EN(14, k3.z) EN(15, k3.w)
            #undef EN
            e0[kt] = r0; e1[kt] = r1;
            k0 = n0; k1 = n1; k2 = n2; k3 = n3;
        }
    }

    // softmax over k (384 = 6 tiles x 64 lanes)
    float m0 = e0[0], m1 = e1[0];
    #pragma unroll
    for (int t = 1; t < 6; ++t) { m0 = fmaxf(m0, e0[t]); m1 = fmaxf(m1, e1[t]); }
    #pragma unroll
    for (int off = 1; off < 64; off <<= 1) {
        m0 = fmaxf(m0, __shfl_xor(m0, off));
        m1 = fmaxf(m1, __shfl_xor(m1, off));
    }
    float a0[6], a1[6], s0 = 0.f, s1 = 0.f;
    #pragma unroll
    for (int t = 0; t < 6; ++t) {
        a0[t] = __builtin_amdgcn_exp2f((e0[t] - m0) * SSCL); s0 += a0[t];
        a1[t] = __builtin_amdgcn_exp2f((e1[t] - m1) * SSCL); s1 += a1[t];
    }
    #pragma unroll
    for (int off = 1; off < 64; off <<= 1) {
        s0 += __shfl_xor(s0, off);
        s1 += __shfl_xor(s1, off);
    }
    float z0 = __builtin_amdgcn_rcpf(s0), z1 = __builtin_amdgcn_rcpf(s1);

    size_t abase = (size_t)bh * SEQ * SEQ + (size_t)q0 * SEQ;
    #pragma unroll
    for (int t = 0; t < 6; ++t) {
        float v0 = a0[t] * z0, v1 = a1[t] * z1;
        attnOut[abase + t * 64 + lane] = v0;
        attnOut[abase + SEQ + t * 64 + lane] = v1;
        aP[wave][t * 64 + lane] = make_float2(v0, v1);
    }
    // no barrier: aP[wave] written and read by the same wave

    // attn @ V: lane = ko*16 + d4p; 4 k-phases, float4 over d, 2 q rows
    int ko = lane >> 4, d4p = lane & 15;
    const float4* vb = (const float4*)&V[(size_t)b * SEQ * HID + h * HD + d4p * 4];
    float4 x0 = make_float4(0.f, 0.f, 0.f, 0.f);
    float4 x1 = make_float4(0.f, 0.f, 0.f, 0.f);
    #pragma unroll 8
    for (int k = ko; k < SEQ; k += 4) {
        float4 v = vb[(size_t)k * (HID / 4)];
        float2 a = aP[wave][k];
        x0.x = fmaf(a.x, v.x, x0.x); x0.y = fmaf(a.x, v.y, x0.y);
        x0.z = fmaf(a.x, v.z, x0.z); x0.w = fmaf(a.x, v.w, x0.w);
        x1.x = fmaf(a.y, v.x, x1.x); x1.y = fmaf(a.y, v.y, x1.y);
        x1.z = fmaf(a.y, v.z, x1.z); x1.w = fmaf(a.y, v.w, x1.w);
    }
    #pragma unroll
    for (int off = 16; off < 64; off <<= 1) {
        x0.x += __shfl_xor(x0.x, off); x0.y += __shfl_xor(x0.y, off);
        x0.z += __shfl_xor(x0.z, off); x0.w += __shfl_xor(x0.w, off);
        x1.x += __shfl_xor(x1.x, off); x1.y += __shfl_xor(x1.y, off);
        x1.z += __shfl_xor(x1.z, off); x1.w += __shfl_xor(x1.w, off);
    }

    // Pack X rows q0/q1 (this head's 64 cols) straight into Ax.
    // Lanes 0..15 hold the full row as float4; chunk u (8 floats) = lanes {2u,2u+1}.
    if (ko == 0) {
        float4 p0, p1;
        p0.x = __shfl_xor(x0.x, 1); p0.y = __shfl_xor(x0.y, 1);
        p0.z = __shfl_xor(x0.z, 1); p0.w = __shfl_xor(x0.w, 1);
        p1.x = __shfl_xor(x1.x, 1); p1.y = __shfl_xor(x1.y, 1);
        p1.z = __shfl_xor(x1.z, 1); p1.w = __shfl_xor(x1.w, 1);
        float vals[8];
        int row;
        if ((lane & 1) == 0) {
            vals[0] = x0.x; vals[1] = x0.y; vals[2] = x0.z; vals[3] = x0.w;
            vals[4] = p0.x; vals[5] = p0.y; vals[6] = p0.z; vals[7] = p0.w;
            row = b * SEQ + q0;
        } else {
            vals[0] = p1.x; vals[1] = p1.y; vals[2] = p1.z; vals[3] = p1.w;
            vals[4] = x1.x; vals[5] = x1.y; vals[6] = x1.z; vals[7] = x1.w;
            row = b * SEQ + q1;
        }
        int g = h * 8 + (lane >> 1);   // global 8-col group
        s8v hi, lo;
        #pragma unroll
        for (int j = 0; j < 8; ++j) {
            unsigned short hh = bf16_rne(vals[j]);
            hi[j] = (short)hh;
            lo[j] = (short)bf16_rne(vals[j] - bf16_val(hh));
        }
        int mt = row >> 4, kt2 = g >> 2;
        int lanei = (row & 15) | ((g & 3) << 4);
        size_t base = ((size_t)mt * KT_N) * 64 + lanei;
        Ax[base + (size_t)kt2 * 64]        = hi;
        Ax[base + (size_t)(16 + kt2) * 64] = hi;
        Ax[base + (size_t)(32 + kt2) * 64] = lo;
    }
}

// ---------------------------------------------------------------------------
extern "C" void kernel_launch(void* const* d_in, const int* in_sizes, int n_in,
                              void* d_out, int out_size, void* d_ws, size_t ws_size,
                              hipStream_t stream)
{
    const float* query = (const float*)d_in[0];
    const float* key   = (const float*)d_in[1];
    const float* value = (const float*)d_in[2];
    const float* Wq = (const float*)d_in[3];
    const float* bq = (const float*)d_in[4];
    const float* Wk = (const float*)d_in[5];
    const float* bk = (const float*)d_in[6];
    const float* Wv = (const float*)d_in[7];
    const float* bv = (const float*)d_in[8];
    const float* Ww = (const float*)d_in[9];
    const float* bw = (const float*)d_in[10];
    const float* Wu = (const float*)d_in[11];
    const float* bu = (const float*)d_in[12];
    const float* vv = (const float*)d_in[13];
    const float* Wo = (const float*)d_in[14];
    const float* bo = (const float*)d_in[15];

    float* out_x    = (float*)d_out;                 // [2,384,512]
    float* out_attn = out_x + (size_t)MROWS * HID;   // [2,8,384,384]

    float* ws  = (float*)d_ws;
    float* bqe = ws;                 // 512
    float* bke = bqe + 512;          // 512
    float* vv2 = bke + 512;          // 64
    float* EqB = vv2 + 64;           // 393216
    float* Ek4 = EqB + 393216;       // 393216 (transposed-packed)
    float* Vw  = Ek4 + 393216;       // 393216

    s8v* packs = (s8v*)(Vw + 393216);        // 16B-aligned
    s8v* Aq = packs;                          // APACK_S8 each
    s8v* Ak = Aq + APACK_S8;
    s8v* Av = Ak + APACK_S8;
    s8v* Ax = Av + APACK_S8;
    s8v* Bq = Ax + APACK_S8;                  // BPACK_S8 each
    s8v* Bk = Bq + BPACK_S8;
    s8v* Bv = Bk + BPACK_S8;
    s8v* Bo = Bv + BPACK_S8;

    pack_all_kernel<<<dim3(1089), 256, 0, stream>>>(
        query, key, value,
        Wq, bq, Wk, bk, Wv, Wo, Ww, bw, Wu, bu, vv,
        Aq, Ak, Av, Bq, Bk, Bv, Bo,
        bqe, bke, vv2);
    proj3_mfma_kernel<<<dim3(24, 16, 3), 64, 0, stream>>>(Aq, Ak, Av, Bq, Bk, Bv,
                                                          bqe, bke, bv,
                                                          EqB, Ek4, Vw);
    attn_kernel<<<dim3(768), 256, 0, stream>>>(EqB, Ek4, Vw, vv2, out_attn, Ax);
    out_mfma_kernel<<<dim3(24, 16), 64, 0, stream>>>(Ax, Bo, bo, out_x);
}

// Round 11
// 140.582 us; speedup vs baseline: 1.5481x; 1.0295x over previous
//
#include <hip/hip_runtime.h>

#define HID 512
#define HEADS 8
#define HD 64
#define BATCH 2
#define SEQ 384
#define MROWS (BATCH * SEQ)  // 768
// 2-section packs: [Ah | Al] and [Bh | Bl], 16 base k-tiles each (K=512)
#define APACK_S8 (48 * 32 * 64)   // 98304 s8-chunks per packed A
#define BPACK_S8 (32 * 32 * 64)   // 65536 s8-chunks per packed B

// 2*log2(e): Eq = exp2(C1 * qW) == exp(2*qW)
#define C1 2.8853900817779268f
// log2(e)/8: softmax exponent scale (energy = raw/8)
#define SSCL 0.18033688011112043f

typedef __attribute__((ext_vector_type(8))) short s8v;   // 8 bf16 (4 VGPR)
typedef __attribute__((ext_vector_type(4))) float f4v;   // MFMA acc

__device__ __forceinline__ unsigned short bf16_rne(float x) {
    union { float f; unsigned u; } v; v.f = x;
    unsigned r = v.u + 0x7FFFu + ((v.u >> 16) & 1u);
    return (unsigned short)(r >> 16);
}
__device__ __forceinline__ float bf16_val(unsigned short h) {
    union { float f; unsigned u; } v; v.u = ((unsigned)h) << 16; return v.f;
}

// ---------------------------------------------------------------------------
// Pack A [768x512 f32] -> [Ah | Al] bf16 in MFMA swizzle:
// s8 index (mt*32 + sec*16 + kt)*64 + lane, lane = (m&15) | ((g&3)<<4)
// ---------------------------------------------------------------------------
__device__ __forceinline__ void pack_a_one(const float* __restrict__ src,
                                           s8v* __restrict__ dst, int rem)
{
    int g = rem & 63, m = rem >> 6;           // c = 8g .. 8g+7
    const float4* sp = (const float4*)(src + (size_t)m * HID + g * 8);
    float4 v0 = sp[0], v1 = sp[1];
    float vals[8] = {v0.x, v0.y, v0.z, v0.w, v1.x, v1.y, v1.z, v1.w};
    s8v hi, lo;
    #pragma unroll
    for (int j = 0; j < 8; ++j) {
        unsigned short h = bf16_rne(vals[j]);
        hi[j] = (short)h;
        lo[j] = (short)bf16_rne(vals[j] - bf16_val(h));
    }
    int mt = m >> 4, kt = g >> 2;
    int lanei = (m & 15) | ((g & 3) << 4);
    size_t base = ((size_t)mt * 32) * 64 + lanei;
    dst[base + (size_t)kt * 64]        = hi;  // sec0: Ah
    dst[base + (size_t)(16 + kt) * 64] = lo;  // sec1: Al
}

// ---------------------------------------------------------------------------
// Pack W [512x512 f32, (k,n)] -> [Bh | Bl] in MFMA swizzle
// ---------------------------------------------------------------------------
__device__ __forceinline__ void pack_w_store(s8v* __restrict__ dst,
                                             const float vals[8], int kg, int n)
{
    s8v hi, lo;
    #pragma unroll
    for (int j = 0; j < 8; ++j) {
        unsigned short h = bf16_rne(vals[j]);
        hi[j] = (short)h;
        lo[j] = (short)bf16_rne(vals[j] - bf16_val(h));
    }
    int nt = n >> 4, kt = kg >> 2;
    int lanei = (n & 15) | ((kg & 3) << 4);
    size_t base = ((size_t)nt * 32) * 64 + lanei;
    dst[base + (size_t)kt * 64]        = hi;  // sec0: Bh
    dst[base + (size_t)(16 + kt) * 64] = lo;  // sec1: Bl
}

__device__ __forceinline__ void pack_w_one(const float* __restrict__ W,
                                           s8v* __restrict__ dst, int rem)
{
    int kg = rem >> 9, n = rem & 511;         // k = 8kg .. 8kg+7
    float vals[8];
    #pragma unroll
    for (int j = 0; j < 8; ++j)
        vals[j] = W[(size_t)(kg * 8 + j) * HID + n];   // coalesced across n
    pack_w_store(dst, vals, kg, n);
}

// fold Wbig(512x512) @ blockdiag(Wsmall 64x64) on the fly, then pack
__device__ __forceinline__ void fold_pack_w_one(const float* __restrict__ Wbig,
                                                const float* __restrict__ Wsmall,
                                                s8v* __restrict__ dst, int rem)
{
    int kg = __builtin_amdgcn_readfirstlane(rem >> 9);
    int n  = rem & 511;
    int h  = __builtin_amdgcn_readfirstlane(n >> 6);
    int d  = n & 63;
    const float* wr = Wbig + (size_t)(kg * 8) * HID + h * HD;
    float acc[8] = {0.f, 0.f, 0.f, 0.f, 0.f, 0.f, 0.f, 0.f};
    #pragma unroll 8
    for (int t = 0; t < 64; ++t) {
        float wv = Wsmall[t * 64 + d];      // coalesced across lanes
        #pragma unroll
        for (int j = 0; j < 8; ++j)
            acc[j] = fmaf(wr[(size_t)j * HID + t], wv, acc[j]);  // uniform
    }
    pack_w_store(dst, acc, kg, n);
}

// ---------------------------------------------------------------------------
// ONE launch for all prep+pack work (no internal dependencies):
// [0,576): A packs q,k,v | [576,704): Wv | [704,832): Wo
// [832,960): fold(Wq,Ww) | [960,1088): fold(Wk,Wu) | [1088]: biases + vv2
// ---------------------------------------------------------------------------
__global__ __launch_bounds__(256) void pack_all_kernel(
    const float* __restrict__ q, const float* __restrict__ k, const float* __restrict__ v,
    const float* __restrict__ Wq, const float* __restrict__ bq,
    const float* __restrict__ Wk, const float* __restrict__ bk,
    const float* __restrict__ Wv, const float* __restrict__ Wo,
    const float* __restrict__ Ww, const float* __restrict__ bw,
    const float* __restrict__ Wu, const float* __restrict__ bu,
    const float* __restrict__ vv,
    s8v* __restrict__ Aq, s8v* __restrict__ Ak, s8v* __restrict__ Av,
    s8v* __restrict__ Bq, s8v* __restrict__ Bk, s8v* __restrict__ Bv, s8v* __restrict__ Bo,
    float* __restrict__ bqe, float* __restrict__ bke, float* __restrict__ vv2)
{
    int bx = blockIdx.x, tid = threadIdx.x;
    if (bx < 576) {
        int p = bx / 192;
        int rem = (bx % 192) * 256 + tid;
        const float* src = (p == 0) ? q : (p == 1) ? k : v;
        s8v* dst = (p == 0) ? Aq : (p == 1) ? Ak : Av;
        pack_a_one(src, dst, rem);
    } else if (bx < 704) {
        pack_w_one(Wv, Bv, (bx - 576) * 256 + tid);
    } else if (bx < 832) {
        pack_w_one(Wo, Bo, (bx - 704) * 256 + tid);
    } else if (bx < 960) {
        fold_pack_w_one(Wq, Ww, Bq, (bx - 832) * 256 + tid);
    } else if (bx < 1088) {
        fold_pack_w_one(Wk, Wu, Bk, (bx - 960) * 256 + tid);
    } else {
        for (int i = tid; i < 1088; i += 256) {
            if (i < 512) {
                int h = i >> 6, j = i & 63;
                float s = bw[j];
                for (int t = 0; t < 64; ++t) s = fmaf(bq[h * 64 + t], Ww[t * 64 + j], s);
                bqe[i] = s;
            } else if (i < 1024) {
                int n = i - 512, h = n >> 6, j = n & 63;
                float s = bu[j];
                for (int t = 0; t < 64; ++t) s = fmaf(bk[h * 64 + t], Wu[t * 64 + j], s);
                bke[n] = s;
            } else {
                vv2[i - 1024] = -2.0f * vv[i - 1024];
            }
        }
    }
}

// ---------------------------------------------------------------------------
// MFMA GEMM: one WAVE per block (64 thr), 32x32 tile (2x2 MFMA 16x16x32).
// 3-term bf16 split done per base k-tile: AhBh + AhBl + AlBh (12 MFMA / 8 loads)
// No LDS, no barriers; fragments loaded coalesced b128 from 2-section packs.
// MODE 0: plain  MODE 1: exp2(C1*y)  MODE 2: exp2 + transposed-packed Ek4
// ---------------------------------------------------------------------------
struct Frag { s8v ah0, al0, ah1, al1, bh0, bl0, bh1, bl1; };

__device__ __forceinline__ void load_frag(Frag& f,
    const s8v* __restrict__ a0, const s8v* __restrict__ a1,
    const s8v* __restrict__ b0, const s8v* __restrict__ b1, int kt)
{
    int oh = kt * 64, ol = (16 + kt) * 64;
    f.ah0 = a0[oh]; f.al0 = a0[ol];
    f.ah1 = a1[oh]; f.al1 = a1[ol];
    f.bh0 = b0[oh]; f.bl0 = b0[ol];
    f.bh1 = b1[oh]; f.bl1 = b1[ol];
}

__device__ __forceinline__ void compute_frag(f4v& acc00, f4v& acc01,
                                             f4v& acc10, f4v& acc11, const Frag& f)
{
    acc00 = __builtin_amdgcn_mfma_f32_16x16x32_bf16(f.ah0, f.bh0, acc00, 0, 0, 0);
    acc01 = __builtin_amdgcn_mfma_f32_16x16x32_bf16(f.ah0, f.bh1, acc01, 0, 0, 0);
    acc10 = __builtin_amdgcn_mfma_f32_16x16x32_bf16(f.ah1, f.bh0, acc10, 0, 0, 0);
    acc11 = __builtin_amdgcn_mfma_f32_16x16x32_bf16(f.ah1, f.bh1, acc11, 0, 0, 0);
    acc00 = __builtin_amdgcn_mfma_f32_16x16x32_bf16(f.ah0, f.bl0, acc00, 0, 0, 0);
    acc01 = __builtin_amdgcn_mfma_f32_16x16x32_bf16(f.ah0, f.bl1, acc01, 0, 0, 0);
    acc10 = __builtin_amdgcn_mfma_f32_16x16x32_bf16(f.ah1, f.bl0, acc10, 0, 0, 0);
    acc11 = __builtin_amdgcn_mfma_f32_16x16x32_bf16(f.ah1, f.bl1, acc11, 0, 0, 0);
    acc00 = __builtin_amdgcn_mfma_f32_16x16x32_bf16(f.al0, f.bh0, acc00, 0, 0, 0);
    acc01 = __builtin_amdgcn_mfma_f32_16x16x32_bf16(f.al0, f.bh1, acc01, 0, 0, 0);
    acc10 = __builtin_amdgcn_mfma_f32_16x16x32_bf16(f.al1, f.bh0, acc10, 0, 0, 0);
    acc11 = __builtin_amdgcn_mfma_f32_16x16x32_bf16(f.al1, f.bh1, acc11, 0, 0, 0);
}

template <int MODE>
__device__ __forceinline__ void mfma_gemm_body(
    const s8v* __restrict__ Ap, const s8v* __restrict__ Bp,
    const float* __restrict__ bias, float* __restrict__ out,
    int mt0, int nt0)
{
    int lane = threadIdx.x & 63;

    const s8v* a0p = Ap + (size_t)(mt0 * 32) * 64 + lane;
    const s8v* a1p = a0p + (size_t)32 * 64;
    const s8v* b0p = Bp + (size_t)(nt0 * 32) * 64 + lane;
    const s8v* b1p = b0p + (size_t)32 * 64;

    f4v acc00 = {0.f, 0.f, 0.f, 0.f};
    f4v acc01 = {0.f, 0.f, 0.f, 0.f};
    f4v acc10 = {0.f, 0.f, 0.f, 0.f};
    f4v acc11 = {0.f, 0.f, 0.f, 0.f};

    Frag X, Y;
    load_frag(X, a0p, a1p, b0p, b1p, 0);
    #pragma unroll 1
    for (int kt = 0; kt < 16; kt += 2) {
        load_frag(Y, a0p, a1p, b0p, b1p, kt + 1);
        compute_frag(acc00, acc01, acc10, acc11, X);
        load_frag(X, a0p, a1p, b0p, b1p, (kt + 2) & 15);  // tail wraps to 0
        compute_frag(acc00, acc01, acc10, acc11, Y);
    }

    // Epilogue. C/D layout: row = quad*4 + reg, col = lane&15.
    int quad = lane >> 4, c16 = lane & 15;
    int col0 = nt0 * 16 + c16, col1 = col0 + 16;
    float bias0 = bias[col0], bias1 = bias[col1];
    int row0 = mt0 * 16 + quad * 4;
    int row1 = row0 + 16;

    #pragma unroll
    for (int r = 0; r < 4; ++r) {
        float y;
        #define WR(ROW, COL, Y)                                                     \
        {                                                                           \
            float yy = (Y);                                                         \
            if (MODE != 0) yy = __builtin_amdgcn_exp2f(C1 * yy);                    \
            if (MODE == 2) {                                                        \
                int b2 = (ROW) / SEQ, kk = (ROW) - b2 * SEQ;                        \
                int hh = (COL) >> 6, dd = (COL) & 63;                               \
                out[(((size_t)((b2 * 8 + hh) * 16 + (dd >> 2)) * SEQ + kk) << 2)    \
                    + (dd & 3)] = yy;                                               \
            } else {                                                                \
                out[(size_t)(ROW) * HID + (COL)] = yy;                              \
            }                                                                       \
        }
        y = acc00[r] + bias0; WR(row0 + r, col0, y);
        y = acc01[r] + bias1; WR(row0 + r, col1, y);
        y = acc10[r] + bias0; WR(row1 + r, col0, y);
        y = acc11[r] + bias1; WR(row1 + r, col1, y);
        #undef WR
    }
}

__global__ __launch_bounds__(64) void proj3_mfma_kernel(
    const s8v* __restrict__ Aq, const s8v* __restrict__ Ak, const s8v* __restrict__ Av,
    const s8v* __restrict__ Bq, const s8v* __restrict__ Bk, const s8v* __restrict__ Bv,
    const float* __restrict__ bqe, const float* __restrict__ bke, const float* __restrict__ bv,
    float* __restrict__ Eq, float* __restrict__ Ek4, float* __restrict__ V)
{
    int p = blockIdx.z;
    int mt0 = blockIdx.x * 2, nt0 = blockIdx.y * 2;
    if (p == 0)      mfma_gemm_body<1>(Aq, Bq, bqe, Eq,  mt0, nt0);
    else if (p == 1) mfma_gemm_body<2>(Ak, Bk, bke, Ek4, mt0, nt0);
    else             mfma_gemm_body<0>(Av, Bv, bv,  V,   mt0, nt0);
}

__global__ __launch_bounds__(64) void out_mfma_kernel(
    const s8v* __restrict__ Ax, const s8v* __restrict__ Bo,
    const float* __restrict__ bo, float* __restrict__ out)
{
    mfma_gemm_body<0>(Ax, Bo, bo, out, blockIdx.x * 2, blockIdx.y * 2);
}

// ---------------------------------------------------------------------------
// attention (R7 structure + XCD-aware 1-D block swizzle):
// 2 q-rows per wave, 768 blocks = 3 blocks/CU, no barriers.
// Swizzle: xcd = blk & 7; each XCD handles exactly 2 bh slices. Perf-only.
// Eq/vv2 wave-uniform -> scalar; Ek4 coalesced b128, per-chunk prefetch.
// Epilogue packs X directly into Ax (bf16 2-section MFMA swizzle).
// ---------------------------------------------------------------------------
__global__ __launch_bounds__(256, 4) void attn_kernel(
    const float* __restrict__ Eq, const float* __restrict__ Ek4,
    const float* __restrict__ V, const float* __restrict__ vv2,
    float* __restrict__ attnOut, s8v* __restrict__ Ax)
{
    __shared__ float2 aP[4][SEQ];

    int blk = blockIdx.x;
    int xcd = blk & 7, slot = blk >> 3;       // slot in [0,96)
    int part = slot / 48, qblk = slot % 48;
    int bh = xcd * 2 + part;
    int b = bh >> 3, h = bh & 7;
    int tid = threadIdx.x;
    int wave = __builtin_amdgcn_readfirstlane(tid >> 6);
    int lane = tid & 63;
    int q0 = qblk * 8 + wave * 2, q1 = q0 + 1;

    const float* eq0 = Eq + (size_t)(b * SEQ + q0) * HID + h * HD;  // uniform
    const float* eq1 = eq0 + HID;
    const float4* ekbase = (const float4*)Ek4 + (size_t)bh * 16 * SEQ + lane;

    float e0[6], e1[6];
    #pragma unroll
    for (int t = 0; t < 6; ++t) { e0[t] = 0.f; e1[t] = 0.f; }

    #pragma unroll 1
    for (int c = 0; c < 4; ++c) {
        float g0[16], g1[16], w[16];
        #pragma unroll
        for (int j = 0; j < 16; ++j) {
            g0[j] = eq0[c * 16 + j];   // wave-uniform -> s_load
            g1[j] = eq1[c * 16 + j];
            w[j]  = vv2[c * 16 + j];
        }
        const float4* ekc = ekbase + (size_t)c * 4 * SEQ;
        float4 k0 = ekc[0 * SEQ], k1 = ekc[1 * SEQ];
        float4 k2 = ekc[2 * SEQ], k3 = ekc[3 * SEQ];
        #pragma unroll
        for (int kt = 0; kt < 6; ++kt) {
            float4 n0, n1, n2, n3;
            if (kt < 5) {
                const float4* np = ekc + (kt + 1) * 64;
                n0 = np[0 * SEQ]; n1 = np[1 * SEQ];
                n2 = np[2 * SEQ]; n3 = np[3 * SEQ];
            }
            float r0 = e0[kt], r1 = e1[kt];
            #define EN(J, KV)                                                      \
            {                                                                      \
                float t0 = __builtin_amdgcn_rcpf(fmaf(g0[J], (KV), 1.f));          \
                float t1 = __builtin_amdgcn_rcpf(fmaf(g1[J], (KV), 1.f));          \
                r0 = fmaf(w[J], t0, r0);                                           \
                r1 = fmaf(w[J], t1, r1);                                           \
            }
            EN(0,  k0.x) EN(1,  k0.y) EN(2,  k0.z) EN(3,  k0.w)
            EN(4,  k1.x) EN(5,  k1.y) EN(6,  k1.z) EN(7,  k1.w)
            EN(8,  k2.x) EN(9,  k2.y) EN(10, k2.z) EN(11, k2.w)
            EN(12, k3.x) EN(13, k3.y) EN(14, k3.z) EN(15, k3.w)
            #undef EN
            e0[kt] = r0; e1[kt] = r1;
            k0 = n0; k1 = n1; k2 = n2; k3 = n3;
        }
    }

    // softmax over k (384 = 6 tiles x 64 lanes)
    float m0 = e0[0], m1 = e1[0];
    #pragma unroll
    for (int t = 1; t < 6; ++t) { m0 = fmaxf(m0, e0[t]); m1 = fmaxf(m1, e1[t]); }
    #pragma unroll
    for (int off = 1; off < 64; off <<= 1) {
        m0 = fmaxf(m0, __shfl_xor(m0, off));
        m1 = fmaxf(m1, __shfl_xor(m1, off));
    }
    float a0[6], a1[6], s0 = 0.f, s1 = 0.f;
    #pragma unroll
    for (int t = 0; t < 6; ++t) {
        a0[t] = __builtin_amdgcn_exp2f((e0[t] - m0) * SSCL); s0 += a0[t];
        a1[t] = __builtin_amdgcn_exp2f((e1[t] - m1) * SSCL); s1 += a1[t];
    }
    #pragma unroll
    for (int off = 1; off < 64; off <<= 1) {
        s0 += __shfl_xor(s0, off);
        s1 += __shfl_xor(s1, off);
    }
    float z0 = __builtin_amdgcn_rcpf(s0), z1 = __builtin_amdgcn_rcpf(s1);

    size_t abase = (size_t)bh * SEQ * SEQ + (size_t)q0 * SEQ;
    #pragma unroll
    for (int t = 0; t < 6; ++t) {
        float v0 = a0[t] * z0, v1 = a1[t] * z1;
        attnOut[abase + t * 64 + lane] = v0;
        attnOut[abase + SEQ + t * 64 + lane] = v1;
        aP[wave][t * 64 + lane] = make_float2(v0, v1);
    }
    // no barrier: aP[wave] written and read by the same wave

    // attn @ V: lane = ko*16 + d4p; 4 k-phases, float4 over d, 2 q rows
    int ko = lane >> 4, d4p = lane & 15;
    const float4* vb = (const float4*)&V[(size_t)b * SEQ * HID + h * HD + d4p * 4];
    float4 x0 = make_float4(0.f, 0.f, 0.f, 0.f);
    float4 x1 = make_float4(0.f, 0.f, 0.f, 0.f);
    #pragma unroll 8
    for (int k = ko; k < SEQ; k += 4) {
        float4 v = vb[(size_t)k * (HID / 4)];
        float2 a = aP[wave][k];
        x0.x = fmaf(a.x, v.x, x0.x); x0.y = fmaf(a.x, v.y, x0.y);
        x0.z = fmaf(a.x, v.z, x0.z); x0.w = fmaf(a.x, v.w, x0.w);
        x1.x = fmaf(a.y, v.x, x1.x); x1.y = fmaf(a.y, v.y, x1.y);
        x1.z = fmaf(a.y, v.z, x1.z); x1.w = fmaf(a.y, v.w, x1.w);
    }
    #pragma unroll
    for (int off = 16; off < 64; off <<= 1) {
        x0.x += __shfl_xor(x0.x, off); x0.y += __shfl_xor(x0.y, off);
        x0.z += __shfl_xor(x0.z, off); x0.w += __shfl_xor(x0.w, off);
        x1.x += __shfl_xor(x1.x, off); x1.y += __shfl_xor(x1.y, off);
        x1.z += __shfl_xor(x1.z, off); x1.w += __shfl_xor(x1.w, off);
    }

    // Pack X rows q0/q1 (this head's 64 cols) straight into Ax.
    // Lanes 0..15 hold the full row as float4; chunk u (8 floats) = lanes {2u,2u+1}.
    if (ko == 0) {
        float4 p0, p1;
        p0.x = __shfl_xor(x0.x, 1); p0.y = __shfl_xor(x0.y, 1);
        p0.z = __shfl_xor(x0.z, 1); p0.w = __shfl_xor(x0.w, 1);
        p1.x = __shfl_xor(x1.x, 1); p1.y = __shfl_xor(x1.y, 1);
        p1.z = __shfl_xor(x1.z, 1); p1.w = __shfl_xor(x1.w, 1);
        float vals[8];
        int row;
        if ((lane & 1) == 0) {
            vals[0] = x0.x; vals[1] = x0.y; vals[2] = x0.z; vals[3] = x0.w;
            vals[4] = p0.x; vals[5] = p0.y; vals[6] = p0.z; vals[7] = p0.w;
            row = b * SEQ + q0;
        } else {
            vals[0] = p1.x; vals[1] = p1.y; vals[2] = p1.z; vals[3] = p1.w;
            vals[4] = x1.x; vals[5] = x1.y; vals[6] = x1.z; vals[7] = x1.w;
            row = b * SEQ + q1;
        }
        int g = h * 8 + (lane >> 1);   // global 8-col group
        s8v hi, lo;
        #pragma unroll
        for (int j = 0; j < 8; ++j) {
            unsigned short hh = bf16_rne(vals[j]);
            hi[j] = (short)hh;
            lo[j] = (short)bf16_rne(vals[j] - bf16_val(hh));
        }
        int mt = row >> 4, kt2 = g >> 2;
        int lanei = (row & 15) | ((g & 3) << 4);
        size_t base = ((size_t)mt * 32) * 64 + lanei;
        Ax[base + (size_t)kt2 * 64]        = hi;
        Ax[base + (size_t)(16 + kt2) * 64] = lo;
    }
}

// ---------------------------------------------------------------------------
extern "C" void kernel_launch(void* const* d_in, const int* in_sizes, int n_in,
                              void* d_out, int out_size, void* d_ws, size_t ws_size,
                              hipStream_t stream)
{
    const float* query = (const float*)d_in[0];
    const float* key   = (const float*)d_in[1];
    const float* value = (const float*)d_in[2];
    const float* Wq = (const float*)d_in[3];
    const float* bq = (const float*)d_in[4];
    const float* Wk = (const float*)d_in[5];
    const float* bk = (const float*)d_in[6];
    const float* Wv = (const float*)d_in[7];
    const float* bv = (const float*)d_in[8];
    const float* Ww = (const float*)d_in[9];
    const float* bw = (const float*)d_in[10];
    const float* Wu = (const float*)d_in[11];
    const float* bu = (const float*)d_in[12];
    const float* vv = (const float*)d_in[13];
    const float* Wo = (const float*)d_in[14];
    const float* bo = (const float*)d_in[15];

    float* out_x    = (float*)d_out;                 // [2,384,512]
    float* out_attn = out_x + (size_t)MROWS * HID;   // [2,8,384,384]

    float* ws  = (float*)d_ws;
    float* bqe = ws;                 // 512
    float* bke = bqe + 512;          // 512
    float* vv2 = bke + 512;          // 64
    float* EqB = vv2 + 64;           // 393216
    float* Ek4 = EqB + 393216;       // 393216 (transposed-packed)
    float* Vw  = Ek4 + 393216;       // 393216

    s8v* packs = (s8v*)(Vw + 393216);        // 16B-aligned
    s8v* Aq = packs;                          // APACK_S8 each
    s8v* Ak = Aq + APACK_S8;
    s8v* Av = Ak + APACK_S8;
    s8v* Ax = Av + APACK_S8;
    s8v* Bq = Ax + APACK_S8;                  // BPACK_S8 each
    s8v* Bk = Bq + BPACK_S8;
    s8v* Bv = Bk + BPACK_S8;
    s8v* Bo = Bv + BPACK_S8;

    pack_all_kernel<<<dim3(1089), 256, 0, stream>>>(
        query, key, value,
        Wq, bq, Wk, bk, Wv, Wo, Ww, bw, Wu, bu, vv,
        Aq, Ak, Av, Bq, Bk, Bv, Bo,
        bqe, bke, vv2);
    proj3_mfma_kernel<<<dim3(24, 16, 3), 64, 0, stream>>>(Aq, Ak, Av, Bq, Bk, Bv,
                                                          bqe, bke, bv,
                                                          EqB, Ek4, Vw);
    attn_kernel<<<dim3(768), 256, 0, stream>>>(EqB, Ek4, Vw, vv2, out_attn, Ax);
    out_mfma_kernel<<<dim3(24, 16), 64, 0, stream>>>(Ax, Bo, bo, out_x);
}

// Round 12
// 139.588 us; speedup vs baseline: 1.5591x; 1.0071x over previous
//
#include <hip/hip_runtime.h>

#define HID 512
#define HEADS 8
#define HD 64
#define BATCH 2
#define SEQ 384
#define MROWS (BATCH * SEQ)  // 768
// 2-section packs: [Ah | Al] and [Bh | Bl], 16 base k-tiles each (K=512)
#define APACK_S8 (48 * 32 * 64)   // 98304 s8-chunks per packed A
#define BPACK_S8 (32 * 32 * 64)   // 65536 s8-chunks per packed B

// 2*log2(e): Eq = exp2(C1 * qW) == exp(2*qW)
#define C1 2.8853900817779268f
// log2(e)/8: softmax exponent scale (energy = raw/8)
#define SSCL 0.18033688011112043f

typedef __attribute__((ext_vector_type(8))) short s8v;   // 8 bf16 (4 VGPR)
typedef __attribute__((ext_vector_type(4))) float f4v;   // MFMA acc

__device__ __forceinline__ unsigned short bf16_rne(float x) {
    union { float f; unsigned u; } v; v.f = x;
    unsigned r = v.u + 0x7FFFu + ((v.u >> 16) & 1u);
    return (unsigned short)(r >> 16);
}
__device__ __forceinline__ float bf16_val(unsigned short h) {
    union { float f; unsigned u; } v; v.u = ((unsigned)h) << 16; return v.f;
}

// ---------------------------------------------------------------------------
// Pack A [768x512 f32] -> [Ah | Al] bf16 in MFMA swizzle:
// s8 index (mt*32 + sec*16 + kt)*64 + lane, lane = (m&15) | ((g&3)<<4)
// ---------------------------------------------------------------------------
__device__ __forceinline__ void pack_a_one(const float* __restrict__ src,
                                           s8v* __restrict__ dst, int rem)
{
    int g = rem & 63, m = rem >> 6;           // c = 8g .. 8g+7
    const float4* sp = (const float4*)(src + (size_t)m * HID + g * 8);
    float4 v0 = sp[0], v1 = sp[1];
    float vals[8] = {v0.x, v0.y, v0.z, v0.w, v1.x, v1.y, v1.z, v1.w};
    s8v hi, lo;
    #pragma unroll
    for (int j = 0; j < 8; ++j) {
        unsigned short h = bf16_rne(vals[j]);
        hi[j] = (short)h;
        lo[j] = (short)bf16_rne(vals[j] - bf16_val(h));
    }
    int mt = m >> 4, kt = g >> 2;
    int lanei = (m & 15) | ((g & 3) << 4);
    size_t base = ((size_t)mt * 32) * 64 + lanei;
    dst[base + (size_t)kt * 64]        = hi;  // sec0: Ah
    dst[base + (size_t)(16 + kt) * 64] = lo;  // sec1: Al
}

// ---------------------------------------------------------------------------
// Pack W [512x512 f32, (k,n)] -> [Bh | Bl] in MFMA swizzle
// ---------------------------------------------------------------------------
__device__ __forceinline__ void pack_w_store(s8v* __restrict__ dst,
                                             const float vals[8], int kg, int n)
{
    s8v hi, lo;
    #pragma unroll
    for (int j = 0; j < 8; ++j) {
        unsigned short h = bf16_rne(vals[j]);
        hi[j] = (short)h;
        lo[j] = (short)bf16_rne(vals[j] - bf16_val(h));
    }
    int nt = n >> 4, kt = kg >> 2;
    int lanei = (n & 15) | ((kg & 3) << 4);
    size_t base = ((size_t)nt * 32) * 64 + lanei;
    dst[base + (size_t)kt * 64]        = hi;  // sec0: Bh
    dst[base + (size_t)(16 + kt) * 64] = lo;  // sec1: Bl
}

__device__ __forceinline__ void pack_w_one(const float* __restrict__ W,
                                           s8v* __restrict__ dst, int rem)
{
    int kg = rem >> 9, n = rem & 511;         // k = 8kg .. 8kg+7
    float vals[8];
    #pragma unroll
    for (int j = 0; j < 8; ++j)
        vals[j] = W[(size_t)(kg * 8 + j) * HID + n];   // coalesced across n
    pack_w_store(dst, vals, kg, n);
}

// fold Wbig(512x512) @ blockdiag(Wsmall 64x64) on the fly, then pack
__device__ __forceinline__ void fold_pack_w_one(const float* __restrict__ Wbig,
                                                const float* __restrict__ Wsmall,
                                                s8v* __restrict__ dst, int rem)
{
    int kg = __builtin_amdgcn_readfirstlane(rem >> 9);
    int n  = rem & 511;
    int h  = __builtin_amdgcn_readfirstlane(n >> 6);
    int d  = n & 63;
    const float* wr = Wbig + (size_t)(kg * 8) * HID + h * HD;
    float acc[8] = {0.f, 0.f, 0.f, 0.f, 0.f, 0.f, 0.f, 0.f};
    #pragma unroll 8
    for (int t = 0; t < 64; ++t) {
        float wv = Wsmall[t * 64 + d];      // coalesced across lanes
        #pragma unroll
        for (int j = 0; j < 8; ++j)
            acc[j] = fmaf(wr[(size_t)j * HID + t], wv, acc[j]);  // uniform
    }
    pack_w_store(dst, acc, kg, n);
}

// ---------------------------------------------------------------------------
// ONE launch for all prep+pack work (no internal dependencies):
// [0,576): A packs q,k,v | [576,704): Wv | [704,832): Wo
// [832,960): fold(Wq,Ww) | [960,1088): fold(Wk,Wu) | [1088]: biases + vv2
// ---------------------------------------------------------------------------
__global__ __launch_bounds__(256) void pack_all_kernel(
    const float* __restrict__ q, const float* __restrict__ k, const float* __restrict__ v,
    const float* __restrict__ Wq, const float* __restrict__ bq,
    const float* __restrict__ Wk, const float* __restrict__ bk,
    const float* __restrict__ Wv, const float* __restrict__ Wo,
    const float* __restrict__ Ww, const float* __restrict__ bw,
    const float* __restrict__ Wu, const float* __restrict__ bu,
    const float* __restrict__ vv,
    s8v* __restrict__ Aq, s8v* __restrict__ Ak, s8v* __restrict__ Av,
    s8v* __restrict__ Bq, s8v* __restrict__ Bk, s8v* __restrict__ Bv, s8v* __restrict__ Bo,
    float* __restrict__ bqe, float* __restrict__ bke, float* __restrict__ vv2)
{
    int bx = blockIdx.x, tid = threadIdx.x;
    if (bx < 576) {
        int p = bx / 192;
        int rem = (bx % 192) * 256 + tid;
        const float* src = (p == 0) ? q : (p == 1) ? k : v;
        s8v* dst = (p == 0) ? Aq : (p == 1) ? Ak : Av;
        pack_a_one(src, dst, rem);
    } else if (bx < 704) {
        pack_w_one(Wv, Bv, (bx - 576) * 256 + tid);
    } else if (bx < 832) {
        pack_w_one(Wo, Bo, (bx - 704) * 256 + tid);
    } else if (bx < 960) {
        fold_pack_w_one(Wq, Ww, Bq, (bx - 832) * 256 + tid);
    } else if (bx < 1088) {
        fold_pack_w_one(Wk, Wu, Bk, (bx - 960) * 256 + tid);
    } else {
        for (int i = tid; i < 1088; i += 256) {
            if (i < 512) {
                int h = i >> 6, j = i & 63;
                float s = bw[j];
                for (int t = 0; t < 64; ++t) s = fmaf(bq[h * 64 + t], Ww[t * 64 + j], s);
                bqe[i] = s;
            } else if (i < 1024) {
                int n = i - 512, h = n >> 6, j = n & 63;
                float s = bu[j];
                for (int t = 0; t < 64; ++t) s = fmaf(bk[h * 64 + t], Wu[t * 64 + j], s);
                bke[n] = s;
            } else {
                vv2[i - 1024] = -2.0f * vv[i - 1024];
            }
        }
    }
}

// ---------------------------------------------------------------------------
// MFMA GEMM: one WAVE per block (64 thr), 32x32 tile (2x2 MFMA 16x16x32).
// 3-term bf16 split done per base k-tile: AhBh + AhBl + AlBh (12 MFMA / 8 loads)
// No LDS, no barriers; fragments loaded coalesced b128 from 2-section packs.
// MODE 0: plain  MODE 1: exp2(C1*y)  MODE 2: exp2 + transposed-packed Ek4
// ---------------------------------------------------------------------------
struct Frag { s8v ah0, al0, ah1, al1, bh0, bl0, bh1, bl1; };

__device__ __forceinline__ void load_frag(Frag& f,
    const s8v* __restrict__ a0, const s8v* __restrict__ a1,
    const s8v* __restrict__ b0, const s8v* __restrict__ b1, int kt)
{
    int oh = kt * 64, ol = (16 + kt) * 64;
    f.ah0 = a0[oh]; f.al0 = a0[ol];
    f.ah1 = a1[oh]; f.al1 = a1[ol];
    f.bh0 = b0[oh]; f.bl0 = b0[ol];
    f.bh1 = b1[oh]; f.bl1 = b1[ol];
}

__device__ __forceinline__ void compute_frag(f4v& acc00, f4v& acc01,
                                             f4v& acc10, f4v& acc11, const Frag& f)
{
    acc00 = __builtin_amdgcn_mfma_f32_16x16x32_bf16(f.ah0, f.bh0, acc00, 0, 0, 0);
    acc01 = __builtin_amdgcn_mfma_f32_16x16x32_bf16(f.ah0, f.bh1, acc01, 0, 0, 0);
    acc10 = __builtin_amdgcn_mfma_f32_16x16x32_bf16(f.ah1, f.bh0, acc10, 0, 0, 0);
    acc11 = __builtin_amdgcn_mfma_f32_16x16x32_bf16(f.ah1, f.bh1, acc11, 0, 0, 0);
    acc00 = __builtin_amdgcn_mfma_f32_16x16x32_bf16(f.ah0, f.bl0, acc00, 0, 0, 0);
    acc01 = __builtin_amdgcn_mfma_f32_16x16x32_bf16(f.ah0, f.bl1, acc01, 0, 0, 0);
    acc10 = __builtin_amdgcn_mfma_f32_16x16x32_bf16(f.ah1, f.bl0, acc10, 0, 0, 0);
    acc11 = __builtin_amdgcn_mfma_f32_16x16x32_bf16(f.ah1, f.bl1, acc11, 0, 0, 0);
    acc00 = __builtin_amdgcn_mfma_f32_16x16x32_bf16(f.al0, f.bh0, acc00, 0, 0, 0);
    acc01 = __builtin_amdgcn_mfma_f32_16x16x32_bf16(f.al0, f.bh1, acc01, 0, 0, 0);
    acc10 = __builtin_amdgcn_mfma_f32_16x16x32_bf16(f.al1, f.bh0, acc10, 0, 0, 0);
    acc11 = __builtin_amdgcn_mfma_f32_16x16x32_bf16(f.al1, f.bh1, acc11, 0, 0, 0);
}

template <int MODE>
__device__ __forceinline__ void mfma_gemm_body(
    const s8v* __restrict__ Ap, const s8v* __restrict__ Bp,
    const float* __restrict__ bias, float* __restrict__ out,
    int mt0, int nt0)
{
    int lane = threadIdx.x & 63;

    const s8v* a0p = Ap + (size_t)(mt0 * 32) * 64 + lane;
    const s8v* a1p = a0p + (size_t)32 * 64;
    const s8v* b0p = Bp + (size_t)(nt0 * 32) * 64 + lane;
    const s8v* b1p = b0p + (size_t)32 * 64;

    f4v acc00 = {0.f, 0.f, 0.f, 0.f};
    f4v acc01 = {0.f, 0.f, 0.f, 0.f};
    f4v acc10 = {0.f, 0.f, 0.f, 0.f};
    f4v acc11 = {0.f, 0.f, 0.f, 0.f};

    Frag X, Y;
    load_frag(X, a0p, a1p, b0p, b1p, 0);
    #pragma unroll 1
    for (int kt = 0; kt < 16; kt += 2) {
        load_frag(Y, a0p, a1p, b0p, b1p, kt + 1);
        compute_frag(acc00, acc01, acc10, acc11, X);
        load_frag(X, a0p, a1p, b0p, b1p, (kt + 2) & 15);  // tail wraps to 0
        compute_frag(acc00, acc01, acc10, acc11, Y);
    }

    // Epilogue. C/D layout: row = quad*4 + reg, col = lane&15.
    int quad = lane >> 4, c16 = lane & 15;
    int col0 = nt0 * 16 + c16, col1 = col0 + 16;
    float bias0 = bias[col0], bias1 = bias[col1];
    int row0 = mt0 * 16 + quad * 4;
    int row1 = row0 + 16;

    #pragma unroll
    for (int r = 0; r < 4; ++r) {
        float y;
        #define WR(ROW, COL, Y)                                                     \
        {                                                                           \
            float yy = (Y);                                                         \
            if (MODE != 0) yy = __builtin_amdgcn_exp2f(C1 * yy);                    \
            if (MODE == 2) {                                                        \
                int b2 = (ROW) / SEQ, kk = (ROW) - b2 * SEQ;                        \
                int hh = (COL) >> 6, dd = (COL) & 63;                               \
                out[(((size_t)((b2 * 8 + hh) * 16 + (dd >> 2)) * SEQ + kk) << 2)    \
                    + (dd & 3)] = yy;                                               \
            } else {                                                                \
                out[(size_t)(ROW) * HID + (COL)] = yy;                              \
            }                                                                       \
        }
        y = acc00[r] + bias0; WR(row0 + r, col0, y);
        y = acc01[r] + bias1; WR(row0 + r, col1, y);
        y = acc10[r] + bias0; WR(row1 + r, col0, y);
        y = acc11[r] + bias1; WR(row1 + r, col1, y);
        #undef WR
    }
}

__global__ __launch_bounds__(64) void proj3_mfma_kernel(
    const s8v* __restrict__ Aq, const s8v* __restrict__ Ak, const s8v* __restrict__ Av,
    const s8v* __restrict__ Bq, const s8v* __restrict__ Bk, const s8v* __restrict__ Bv,
    const float* __restrict__ bqe, const float* __restrict__ bke, const float* __restrict__ bv,
    float* __restrict__ Eq, float* __restrict__ Ek4, float* __restrict__ V)
{
    int p = blockIdx.z;
    int mt0 = blockIdx.x * 2, nt0 = blockIdx.y * 2;
    if (p == 0)      mfma_gemm_body<1>(Aq, Bq, bqe, Eq,  mt0, nt0);
    else if (p == 1) mfma_gemm_body<2>(Ak, Bk, bke, Ek4, mt0, nt0);
    else             mfma_gemm_body<0>(Av, Bv, bv,  V,   mt0, nt0);
}

__global__ __launch_bounds__(64) void out_mfma_kernel(
    const s8v* __restrict__ Ax, const s8v* __restrict__ Bo,
    const float* __restrict__ bo, float* __restrict__ out)
{
    mfma_gemm_body<0>(Ax, Bo, bo, out, blockIdx.x * 2, blockIdx.y * 2);
}

// ---------------------------------------------------------------------------
// attention (R11 + per-wave rotated d-chunk order + V prefetch over softmax):
// 2 q-rows per wave, 768 blocks = 3 blocks/CU, no barriers.
// XCD swizzle: xcd = blk & 7; each XCD handles exactly 2 bh slices.
// Rotation: wave w starts at d-chunk w&3 -> 4 distinct Ek address streams per
// block (decorrelated miss bursts); chunk order doesn't change the d-sum.
// Eq/vv2 wave-uniform -> scalar; Ek4 coalesced b128, per-chunk prefetch.
// Epilogue packs X directly into Ax (bf16 2-section MFMA swizzle).
// ---------------------------------------------------------------------------
__global__ __launch_bounds__(256, 4) void attn_kernel(
    const float* __restrict__ Eq, const float* __restrict__ Ek4,
    const float* __restrict__ V, const float* __restrict__ vv2,
    float* __restrict__ attnOut, s8v* __restrict__ Ax)
{
    __shared__ float2 aP[4][SEQ];

    int blk = blockIdx.x;
    int xcd = blk & 7, slot = blk >> 3;       // slot in [0,96)
    int part = slot / 48, qblk = slot % 48;
    int bh = xcd * 2 + part;
    int b = bh >> 3, h = bh & 7;
    int tid = threadIdx.x;
    int wave = __builtin_amdgcn_readfirstlane(tid >> 6);
    int lane = tid & 63;
    int q0 = qblk * 8 + wave * 2, q1 = q0 + 1;

    const float* eq0 = Eq + (size_t)(b * SEQ + q0) * HID + h * HD;  // uniform
    const float* eq1 = eq0 + HID;
    const float4* ekbase = (const float4*)Ek4 + (size_t)bh * 16 * SEQ + lane;

    float e0[6], e1[6];
    #pragma unroll
    for (int t = 0; t < 6; ++t) { e0[t] = 0.f; e1[t] = 0.f; }

    #pragma unroll 1
    for (int cc = 0; cc < 4; ++cc) {
        int c = (cc + wave) & 3;          // wave-rotated chunk order (uniform)
        float g0[16], g1[16], w[16];
        #pragma unroll
        for (int j = 0; j < 16; ++j) {
            g0[j] = eq0[c * 16 + j];   // wave-uniform -> s_load
            g1[j] = eq1[c * 16 + j];
            w[j]  = vv2[c * 16 + j];
        }
        const float4* ekc = ekbase + (size_t)c * 4 * SEQ;
        float4 k0 = ekc[0 * SEQ], k1 = ekc[1 * SEQ];
        float4 k2 = ekc[2 * SEQ], k3 = ekc[3 * SEQ];
        #pragma unroll
        for (int kt = 0; kt < 6; ++kt) {
            float4 n0, n1, n2, n3;
            if (kt < 5) {
                const float4* np = ekc + (kt + 1) * 64;
                n0 = np[0 * SEQ]; n1 = np[1 * SEQ];
                n2 = np[2 * SEQ]; n3 = np[3 * SEQ];
            }
            float r0 = e0[kt], r1 = e1[kt];
            #define EN(J, KV)                                                      \
            {                                                                      \
                float t0 = __builtin_amdgcn_rcpf(fmaf(g0[J], (KV), 1.f));          \
                float t1 = __builtin_amdgcn_rcpf(fmaf(g1[J], (KV), 1.f));          \
                r0 = fmaf(w[J], t0, r0);                                           \
                r1 = fmaf(w[J], t1, r1);                                           \
            }
            EN(0,  k0.x) EN(1,  k0.y) EN(2,  k0.z) EN(3,  k0.w)
            EN(4,  k1.x) EN(5,  k1.y) EN(6,  k1.z) EN(7,  k1.w)
            EN(8,  k2.x) EN(9,  k2.y) EN(10, k2.z) EN(11, k2.w)
            EN(12, k3.x) EN(13, k3.y) EN(14, k3.z) EN(15, k3.w)
            #undef EN
            e0[kt] = r0; e1[kt] = r1;
            k0 = n0; k1 = n1; k2 = n2; k3 = n3;
        }
    }

    // Prefetch first 8 V vectors for the attn@V phase (independent of softmax)
    int ko = lane >> 4, d4p = lane & 15;
    const float4* vb = (const float4*)&V[(size_t)b * SEQ * HID + h * HD + d4p * 4];
    float4 vpre[8];
    #pragma unroll
    for (int i = 0; i < 8; ++i)
        vpre[i] = vb[(size_t)(ko + i * 4) * (HID / 4)];

    // softmax over k (384 = 6 tiles x 64 lanes)
    float m0 = e0[0], m1 = e1[0];
    #pragma unroll
    for (int t = 1; t < 6; ++t) { m0 = fmaxf(m0, e0[t]); m1 = fmaxf(m1, e1[t]); }
    #pragma unroll
    for (int off = 1; off < 64; off <<= 1) {
        m0 = fmaxf(m0, __shfl_xor(m0, off));
        m1 = fmaxf(m1, __shfl_xor(m1, off));
    }
    float a0[6], a1[6], s0 = 0.f, s1 = 0.f;
    #pragma unroll
    for (int t = 0; t < 6; ++t) {
        a0[t] = __builtin_amdgcn_exp2f((e0[t] - m0) * SSCL); s0 += a0[t];
        a1[t] = __builtin_amdgcn_exp2f((e1[t] - m1) * SSCL); s1 += a1[t];
    }
    #pragma unroll
    for (int off = 1; off < 64; off <<= 1) {
        s0 += __shfl_xor(s0, off);
        s1 += __shfl_xor(s1, off);
    }
    float z0 = __builtin_amdgcn_rcpf(s0), z1 = __builtin_amdgcn_rcpf(s1);

    size_t abase = (size_t)bh * SEQ * SEQ + (size_t)q0 * SEQ;
    #pragma unroll
    for (int t = 0; t < 6; ++t) {
        float v0 = a0[t] * z0, v1 = a1[t] * z1;
        attnOut[abase + t * 64 + lane] = v0;
        attnOut[abase + SEQ + t * 64 + lane] = v1;
        aP[wave][t * 64 + lane] = make_float2(v0, v1);
    }
    // no barrier: aP[wave] written and read by the same wave

    // attn @ V: lane = ko*16 + d4p; 4 k-phases, float4 over d, 2 q rows.
    // First 8 iterations use the prefetched vectors.
    float4 x0 = make_float4(0.f, 0.f, 0.f, 0.f);
    float4 x1 = make_float4(0.f, 0.f, 0.f, 0.f);
    #pragma unroll
    for (int i = 0; i < 8; ++i) {
        int k = ko + i * 4;
        float4 v = vpre[i];
        float2 a = aP[wave][k];
        x0.x = fmaf(a.x, v.x, x0.x); x0.y = fmaf(a.x, v.y, x0.y);
        x0.z = fmaf(a.x, v.z, x0.z); x0.w = fmaf(a.x, v.w, x0.w);
        x1.x = fmaf(a.y, v.x, x1.x); x1.y = fmaf(a.y, v.y, x1.y);
        x1.z = fmaf(a.y, v.z, x1.z); x1.w = fmaf(a.y, v.w, x1.w);
    }
    #pragma unroll 8
    for (int k = ko + 32; k < SEQ; k += 4) {
        float4 v = vb[(size_t)k * (HID / 4)];
        float2 a = aP[wave][k];
        x0.x = fmaf(a.x, v.x, x0.x); x0.y = fmaf(a.x, v.y, x0.y);
        x0.z = fmaf(a.x, v.z, x0.z); x0.w = fmaf(a.x, v.w, x0.w);
        x1.x = fmaf(a.y, v.x, x1.x); x1.y = fmaf(a.y, v.y, x1.y);
        x1.z = fmaf(a.y, v.z, x1.z); x1.w = fmaf(a.y, v.w, x1.w);
    }
    #pragma unroll
    for (int off = 16; off < 64; off <<= 1) {
        x0.x += __shfl_xor(x0.x, off); x0.y += __shfl_xor(x0.y, off);
        x0.z += __shfl_xor(x0.z, off); x0.w += __shfl_xor(x0.w, off);
        x1.x += __shfl_xor(x1.x, off); x1.y += __shfl_xor(x1.y, off);
        x1.z += __shfl_xor(x1.z, off); x1.w += __shfl_xor(x1.w, off);
    }

    // Pack X rows q0/q1 (this head's 64 cols) straight into Ax.
    // Lanes 0..15 hold the full row as float4; chunk u (8 floats) = lanes {2u,2u+1}.
    if (ko == 0) {
        float4 p0, p1;
        p0.x = __shfl_xor(x0.x, 1); p0.y = __shfl_xor(x0.y, 1);
        p0.z = __shfl_xor(x0.z, 1); p0.w = __shfl_xor(x0.w, 1);
        p1.x = __shfl_xor(x1.x, 1); p1.y = __shfl_xor(x1.y, 1);
        p1.z = __shfl_xor(x1.z, 1); p1.w = __shfl_xor(x1.w, 1);
        float vals[8];
        int row;
        if ((lane & 1) == 0) {
            vals[0] = x0.x; vals[1] = x0.y; vals[2] = x0.z; vals[3] = x0.w;
            vals[4] = p0.x; vals[5] = p0.y; vals[6] = p0.z; vals[7] = p0.w;
            row = b * SEQ + q0;
        } else {
            vals[0] = p1.x; vals[1] = p1.y; vals[2] = p1.z; vals[3] = p1.w;
            vals[4] = x1.x; vals[5] = x1.y; vals[6] = x1.z; vals[7] = x1.w;
            row = b * SEQ + q1;
        }
        int g = h * 8 + (lane >> 1);   // global 8-col group
        s8v hi, lo;
        #pragma unroll
        for (int j = 0; j < 8; ++j) {
            unsigned short hh = bf16_rne(vals[j]);
            hi[j] = (short)hh;
            lo[j] = (short)bf16_rne(vals[j] - bf16_val(hh));
        }
        int mt = row >> 4, kt2 = g >> 2;
        int lanei = (row & 15) | ((g & 3) << 4);
        size_t base = ((size_t)mt * 32) * 64 + lanei;
        Ax[base + (size_t)kt2 * 64]        = hi;
        Ax[base + (size_t)(16 + kt2) * 64] = lo;
    }
}

// ---------------------------------------------------------------------------
extern "C" void kernel_launch(void* const* d_in, const int* in_sizes, int n_in,
                              void* d_out, int out_size, void* d_ws, size_t ws_size,
                              hipStream_t stream)
{
    const float* query = (const float*)d_in[0];
    const float* key   = (const float*)d_in[1];
    const float* value = (const float*)d_in[2];
    const float* Wq = (const float*)d_in[3];
    const float* bq = (const float*)d_in[4];
    const float* Wk = (const float*)d_in[5];
    const float* bk = (const float*)d_in[6];
    const float* Wv = (const float*)d_in[7];
    const float* bv = (const float*)d_in[8];
    const float* Ww = (const float*)d_in[9];
    const float* bw = (const float*)d_in[10];
    const float* Wu = (const float*)d_in[11];
    const float* bu = (const float*)d_in[12];
    const float* vv = (const float*)d_in[13];
    const float* Wo = (const float*)d_in[14];
    const float* bo = (const float*)d_in[15];

    float* out_x    = (float*)d_out;                 // [2,384,512]
    float* out_attn = out_x + (size_t)MROWS * HID;   // [2,8,384,384]

    float* ws  = (float*)d_ws;
    float* bqe = ws;                 // 512
    float* bke = bqe + 512;          // 512
    float* vv2 = bke + 512;          // 64
    float* EqB = vv2 + 64;           // 393216
    float* Ek4 = EqB + 393216;       // 393216 (transposed-packed)
    float* Vw  = Ek4 + 393216;       // 393216

    s8v* packs = (s8v*)(Vw + 393216);        // 16B-aligned
    s8v* Aq = packs;                          // APACK_S8 each
    s8v* Ak = Aq + APACK_S8;
    s8v* Av = Ak + APACK_S8;
    s8v* Ax = Av + APACK_S8;
    s8v* Bq = Ax + APACK_S8;                  // BPACK_S8 each
    s8v* Bk = Bq + BPACK_S8;
    s8v* Bv = Bk + BPACK_S8;
    s8v* Bo = Bv + BPACK_S8;

    pack_all_kernel<<<dim3(1089), 256, 0, stream>>>(
        query, key, value,
        Wq, bq, Wk, bk, Wv, Wo, Ww, bw, Wu, bu, vv,
        Aq, Ak, Av, Bq, Bk, Bv, Bo,
        bqe, bke, vv2);
    proj3_mfma_kernel<<<dim3(24, 16, 3), 64, 0, stream>>>(Aq, Ak, Av, Bq, Bk, Bv,
                                                          bqe, bke, bv,
                                                          EqB, Ek4, Vw);
    attn_kernel<<<dim3(768), 256, 0, stream>>>(EqB, Ek4, Vw, vv2, out_attn, Ax);
    out_mfma_kernel<<<dim3(24, 16), 64, 0, stream>>>(Ax, Bo, bo, out_x);
}